// Round 14
// baseline (1337.308 us; speedup 1.0000x reference)
//
#include <hip/hip_runtime.h>
#include <hip/hip_bf16.h>
#include <cmath>

constexpr int B = 128, L = 100, CIN = 55, COUT = 55;
constexpr int D = 512, H = 8, DFF = 512, MODES = 32, E = 64;
constexpr int NK = 2;
constexpr int M_ROWS = B * L; // 12800
constexpr int KEMB = 192;     // 55*3=165 padded to 32*6
constexpr size_t BLD  = (size_t)B * L * D;         // 6,553,600
constexpr size_t BHEM = (size_t)B * H * E * MODES; // 2,097,152 complex elems
constexpr size_t BHLL = (size_t)B * H * L * L;     // 10,240,000
constexpr float INV_SQRT_2PI = 0.3989422804014327f;

static inline int cdiv(int a, int b) { return (a + b - 1) / b; }

typedef short shortx8 __attribute__((ext_vector_type(8)));
typedef float f32x4 __attribute__((ext_vector_type(4)));

__device__ inline unsigned short f2bf(float f)    // RNE (weight prep)
{
    unsigned int u = __float_as_uint(f);
    unsigned int r = (u + 0x7FFFu + ((u >> 16) & 1u)) >> 16;
    return (unsigned short)r;
}
__device__ inline unsigned short f2bf_n(float f)  // native cvt
{
    union { __hip_bfloat16 h; unsigned short u; } cv;
    cv.h = __float2bfloat16(f);
    return cv.u;
}
__device__ inline float bf2f(unsigned short u)
{
    union { unsigned int i; float f; } c;
    c.i = (unsigned int)u << 16;
    return c.f;
}

// ---------------- constants ----------------
__global__ void init_consts(float* __restrict__ pe)
{
    int idx = blockIdx.x * 256 + threadIdx.x;
    if (idx < L * D) {
        int l = idx / D, d = idx % D;
        int i2 = d & ~1;
        float div = expf((float)i2 * (-logf(10000.f) / (float)D));
        float ang = (float)l * div;
        pe[idx] = (d & 1) ? cosf(ang) : sinf(ang);
    }
}

// bf16 twiddle tables for MFMA DFT/iDFT
__global__ void init_tw(unsigned short* __restrict__ twf, unsigned short* __restrict__ twi)
{
    int idx = blockIdx.x * 256 + threadIdx.x;
    if (idx >= 64 * 128) return;
    {
        int mp = idx / 128, t = idx % 128;
        float v = 0.f;
        if (t < L) {
            if (mp < 32) v = cosf(2.f * 3.14159265358979323846f * (float)mp * (float)t / (float)L);
            else v = -sinf(2.f * 3.14159265358979323846f * (float)(mp - 32) * (float)t / (float)L);
        }
        twf[idx] = f2bf(v);
    }
    {
        int t = idx / 64, mp = idx % 64;
        float v = 0.f;
        if (t < L) {
            if (mp == 0) v = 1.f;
            else if (mp < 32) v = 2.f * cosf(2.f * 3.14159265358979323846f * (float)mp * (float)t / (float)L);
            else if (mp == 32) v = 0.f;
            else v = -2.f * sinf(2.f * 3.14159265358979323846f * (float)(mp - 32) * (float)t / (float)L);
        }
        twi[idx] = f2bf(v);
    }
}

__global__ void xmean_kernel(const float* __restrict__ x, float* __restrict__ xm)
{
    int idx = blockIdx.x * 256 + threadIdx.x;
    if (idx >= B * CIN) return;
    int b = idx / CIN, c = idx % CIN;
    float s = 0.f;
    for (int l = 0; l < L; ++l) s += x[((size_t)b * L + l) * CIN + c];
    xm[idx] = s * (1.f / (float)L);
}

// ---------------- single merged weight-prep kernel ----------------
struct PrepArgs {
    const float* src[7];
    unsigned short* dst[7];
    int n4[7];               // float4 count per segment
    const float* emb_enc; const float* emb_dec; const float* trend_w; const float* seas_w;
    unsigned short* d_embenc; unsigned short* d_embdec; unsigned short* d_trd; unsigned short* d_seas;
};
__global__ __launch_bounds__(256) void prep_all(PrepArgs a, int total4, int padTotal)
{
    for (int i = blockIdx.x * 256 + threadIdx.x; i < total4 + padTotal; i += gridDim.x * 256) {
        if (i < total4) {
            int idx = i, s = 0;
            while (idx >= a.n4[s]) { idx -= a.n4[s]; ++s; }
            float4 v = *(const float4*)&a.src[s][(size_t)idx * 4];
            ushort4 h;
            h.x = f2bf(v.x); h.y = f2bf(v.y); h.z = f2bf(v.z); h.w = f2bf(v.w);
            *(ushort4*)&a.dst[s][(size_t)idx * 4] = h;
            continue;
        }
        int p = i - total4;
        if (p < D * KEMB) {
            int r = p / KEMB, k = p % KEMB;
            a.d_embenc[p] = (k < CIN * 3) ? f2bf(a.emb_enc[(size_t)r * (CIN * 3) + k]) : (unsigned short)0;
        } else if ((p -= D * KEMB) < D * KEMB) {
            int r = p / KEMB, k = p % KEMB;
            a.d_embdec[p] = (k < CIN * 3) ? f2bf(a.emb_dec[(size_t)r * (CIN * 3) + k]) : (unsigned short)0;
        } else if ((p -= D * KEMB) < 192 * D) {
            int n = p / D, d = p % D;
            int j = n / 64, o = n % 64;
            a.d_trd[p] = (o < COUT) ? f2bf(a.trend_w[(size_t)o * (D * 3) + d * 3 + j]) : (unsigned short)0;
        } else {
            p -= 192 * D;
            int r = p / D, k = p % D;
            a.d_seas[p] = (r < COUT) ? f2bf(a.seas_w[(size_t)r * D + k]) : (unsigned short)0;
        }
    }
}

__global__ __launch_bounds__(256) void transpose_w(const float* __restrict__ wr, const float* __restrict__ wi,
                                                   float2* __restrict__ wt)
{
    int h = blockIdx.x / E, e = blockIdx.x % E;
    __shared__ float tr[64][33], ti[64][33];
    for (int i = threadIdx.x; i < E * MODES; i += 256) {
        int o = i / MODES, m = i % MODES;
        size_t s = (((size_t)h * E + e) * E + o) * MODES + m;
        tr[o][m] = wr[s]; ti[o][m] = wi[s];
    }
    __syncthreads();
    for (int i = threadIdx.x; i < MODES * E; i += 256) {
        int m = i / E, o = i % E;
        wt[(((size_t)h * MODES + m) * E + e) * E + o] = make_float2(tr[o][m], ti[o][m]);
    }
}

// im2col for kernel-3 circular conv: bf16 out
__global__ void im2col_emb(const float* __restrict__ x, const float* __restrict__ xmean,
                           unsigned short* __restrict__ A2)
{
    int idx = blockIdx.x * 256 + threadIdx.x;
    if (idx >= M_ROWS * KEMB) return;
    int k = idx % KEMB, m = idx / KEMB;
    float v = 0.f;
    if (k < CIN * 3) {
        int c = k / 3, j = k % 3;
        int l = m % L, b = m / L;
        int ls = l + j - 1; ls = (ls + L) % L;
        v = x[((size_t)b * L + ls) * CIN + c];
        if (xmean) v -= xmean[(size_t)b * CIN + c];
    }
    A2[idx] = f2bf(v);
}

// ---------------- bf16 MFMA GEMM, double-buffered LDS, ONE barrier per K-step ----------------
// optional residual epilogue: v += bf2f(resid[row*Nout+col]) (resid bf16, same shape as out)
template<int BN>
__global__ __launch_bounds__(256) void gemm_mfma(const unsigned short* __restrict__ A,
                                                 const unsigned short* __restrict__ Wb,
                                                 const float* __restrict__ bias, const float* __restrict__ pe,
                                                 const unsigned short* __restrict__ resid,
                                                 float* __restrict__ C, unsigned short* __restrict__ Cb,
                                                 int Nout, int K, int act, int accum)
{
    constexpr int NI = BN / 32;
    constexpr int BI = BN / 64;
    __shared__ unsigned short As[2][128][40];
    __shared__ unsigned short Bs[2][BN][40];
    int tid = threadIdx.x;
    int row0 = blockIdx.y * 128, col0 = blockIdx.x * BN;
    int wid = tid >> 6, lane = tid & 63;
    int wm = wid >> 1, wn = wid & 1;
    int lrow = lane & 15, kg = lane >> 4;
    int ar = tid >> 2, ac8 = (tid & 3) * 8;
    f32x4 acc[4][NI] = {};
    shortx8 rah[2], rbh[BI];

    auto loadG = [&](int k0) {
#pragma unroll
        for (int p = 0; p < 2; ++p)
            rah[p] = *(const shortx8*)&A[(size_t)(row0 + p * 64 + ar) * K + k0 + ac8];
#pragma unroll
        for (int p = 0; p < BI; ++p)
            rbh[p] = *(const shortx8*)&Wb[(size_t)(col0 + p * 64 + ar) * K + k0 + ac8];
    };
    auto storeLDS = [&](int buf) {
#pragma unroll
        for (int p = 0; p < 2; ++p)
            *(shortx8*)&As[buf][p * 64 + ar][ac8] = rah[p];
#pragma unroll
        for (int p = 0; p < BI; ++p)
            *(shortx8*)&Bs[buf][p * 64 + ar][ac8] = rbh[p];
    };

    int nk = K >> 5;
    loadG(0);
    storeLDS(0);
    if (nk > 1) loadG(32);
    __syncthreads();
    int cur = 0;
    for (int s = 0; s < nk; ++s) {
        if (s + 1 < nk) {
            storeLDS(cur ^ 1);                 // tile s+1 (regs) -> other buffer
            if (s + 2 < nk) loadG((s + 2) << 5); // issue loads for tile s+2
        }
        shortx8 av[4], bv[NI];
#pragma unroll
        for (int mi = 0; mi < 4; ++mi)
            av[mi] = *(const shortx8*)&As[cur][wm * 64 + mi * 16 + lrow][kg * 8];
#pragma unroll
        for (int ni = 0; ni < NI; ++ni)
            bv[ni] = *(const shortx8*)&Bs[cur][wn * (BN / 2) + ni * 16 + lrow][kg * 8];
#pragma unroll
        for (int mi = 0; mi < 4; ++mi)
#pragma unroll
            for (int ni = 0; ni < NI; ++ni)
                acc[mi][ni] = __builtin_amdgcn_mfma_f32_16x16x32_bf16(av[mi], bv[ni], acc[mi][ni], 0, 0, 0);
        if (s + 1 < nk) __syncthreads();
        cur ^= 1;
    }
#pragma unroll
    for (int mi = 0; mi < 4; ++mi) {
#pragma unroll
        for (int ni = 0; ni < NI; ++ni) {
            int col = col0 + wn * (BN / 2) + ni * 16 + lrow;
            if (col >= Nout) continue;
#pragma unroll
            for (int r = 0; r < 4; ++r) {
                int row = row0 + wm * 64 + mi * 16 + kg * 4 + r;
                float v = acc[mi][ni][r];
                if (bias) v += bias[col];
                if (pe) v += pe[(size_t)(row % L) * Nout + col];
                size_t o = (size_t)row * Nout + col;
                if (resid) v += bf2f(resid[o]);
                if (act) v = 0.5f * v * (1.f + erff(v * 0.70710678118654752f));
                if (Cb) Cb[o] = f2bf_n(v);
                else if (accum) C[o] += v;
                else C[o] = v;
            }
        }
    }
}

// ---------------- fused QK^T/8 + row-softmax (bf16 input, row stride 1024) ----------------
__global__ __launch_bounds__(256) void scores_softmax(const unsigned short* __restrict__ QK,
                                                      float* __restrict__ out)
{
    int bh = blockIdx.x, b = bh / H, h = bh % H;
    int pass = blockIdx.y;
    __shared__ unsigned short Ks[112][72];
    __shared__ unsigned short Qs[64][72];
    int tid = threadIdx.x;
    int srow = tid >> 4, sc4 = (tid & 15) * 4;
#pragma unroll
    for (int i = 0; i < 7; ++i) {
        int r = i * 16 + srow;
        ushort4 hh = {0, 0, 0, 0};
        if (r < L) hh = *(const ushort4*)&QK[((size_t)b * L + r) * 1024 + 512 + h * E + sc4];
        *(ushort4*)&Ks[r][sc4] = hh;
    }
#pragma unroll
    for (int i = 0; i < 4; ++i) {
        int r = i * 16 + srow;
        int gr = pass * 64 + r;
        ushort4 hh = {0, 0, 0, 0};
        if (gr < L) hh = *(const ushort4*)&QK[((size_t)b * L + gr) * 1024 + h * E + sc4];
        *(ushort4*)&Qs[r][sc4] = hh;
    }
    __syncthreads();
    int wid = tid >> 6, lane = tid & 63;
    int lrow = lane & 15, kg = lane >> 4;
    f32x4 acc[7] = {};
#pragma unroll
    for (int ks = 0; ks < 2; ++ks) {
        shortx8 aq = *(const shortx8*)&Qs[wid * 16 + lrow][ks * 32 + kg * 8];
#pragma unroll
        for (int tj = 0; tj < 7; ++tj) {
            shortx8 bk = *(const shortx8*)&Ks[tj * 16 + lrow][ks * 32 + kg * 8];
            acc[tj] = __builtin_amdgcn_mfma_f32_16x16x32_bf16(aq, bk, acc[tj], 0, 0, 0);
        }
    }
    float mx[4] = {-1e30f, -1e30f, -1e30f, -1e30f};
#pragma unroll
    for (int tj = 0; tj < 7; ++tj) {
        bool valid = (tj * 16 + lrow) < L;
#pragma unroll
        for (int r = 0; r < 4; ++r) {
            float v = acc[tj][r] * 0.125f;
            acc[tj][r] = valid ? v : -1e30f;
            if (valid) mx[r] = fmaxf(mx[r], v);
        }
    }
#pragma unroll
    for (int off = 1; off < 16; off <<= 1)
#pragma unroll
        for (int r = 0; r < 4; ++r) mx[r] = fmaxf(mx[r], __shfl_xor(mx[r], off));
    float sum[4] = {0.f, 0.f, 0.f, 0.f};
#pragma unroll
    for (int tj = 0; tj < 7; ++tj)
#pragma unroll
        for (int r = 0; r < 4; ++r) {
            float e = expf(acc[tj][r] - mx[r]);
            acc[tj][r] = e;
            sum[r] += e;
        }
#pragma unroll
    for (int off = 1; off < 16; off <<= 1)
#pragma unroll
        for (int r = 0; r < 4; ++r) sum[r] += __shfl_xor(sum[r], off);
    float inv[4];
#pragma unroll
    for (int r = 0; r < 4; ++r) inv[r] = 1.f / sum[r];
    float* base = out + (size_t)bh * L * L;
#pragma unroll
    for (int r = 0; r < 4; ++r) {
        int row = pass * 64 + wid * 16 + kg * 4 + r;
        if (row >= L) continue;
#pragma unroll
        for (int tj = 0; tj < 7; ++tj) {
            int col = tj * 16 + lrow;
            if (col < L) base[(size_t)row * L + col] = acc[tj][r] * inv[r];
        }
    }
}

// trend combine (Y fp32, row stride 192)
__global__ void trend_combine(const float* __restrict__ Y, const float* __restrict__ xmean,
                              float* __restrict__ dec_out)
{
    int idx = blockIdx.x * 256 + threadIdx.x;
    if (idx >= B * L * COUT) return;
    int o = idx % COUT; int l = (idx / COUT) % L; int b = idx / (COUT * L);
    int lm = (l + L - 1) % L, lp = (l + 1) % L;
    float v = xmean[(size_t)b * CIN + o]
            + Y[((size_t)b * L + lm) * 192 + o]
            + Y[((size_t)b * L + l ) * 192 + 64 + o]
            + Y[((size_t)b * L + lp) * 192 + 128 + o];
    dec_out[idx] = v;
}

// ---------------- MFMA forward DFT ----------------
__global__ __launch_bounds__(256) void dft_mfma(const unsigned short* __restrict__ X,
                                                const unsigned short* __restrict__ twf,
                                                float2* __restrict__ xf, int stride)
{
    int b = blockIdx.x / H, h = blockIdx.x % H;
    __shared__ unsigned short Xs[64][136];   // [e][t], t padded to 128
    int tid = threadIdx.x;
    for (int i = tid; i < L * E / 4; i += 256) {
        int t = i >> 4, e4 = (i & 15) * 4;
        ushort4 u = *(const ushort4*)&X[((size_t)b * L + t) * stride + h * E + e4];
        Xs[e4][t] = u.x; Xs[e4 + 1][t] = u.y; Xs[e4 + 2][t] = u.z; Xs[e4 + 3][t] = u.w;
    }
    for (int i = tid; i < 64 * 28; i += 256) {
        int e = i / 28, t = L + i % 28;
        Xs[e][t] = 0;
    }
    __syncthreads();
    int wid = tid >> 6, lane = tid & 63;
    int lrow = lane & 15, kg = lane >> 4;
    f32x4 acc[4] = {};
#pragma unroll
    for (int k0 = 0; k0 < 4; ++k0) {
        shortx8 bx = *(const shortx8*)&Xs[wid * 16 + lrow][k0 * 32 + kg * 8];
#pragma unroll
        for (int mi = 0; mi < 4; ++mi) {
            shortx8 aw = *(const shortx8*)&twf[(size_t)(mi * 16 + lrow) * 128 + k0 * 32 + kg * 8];
            acc[mi] = __builtin_amdgcn_mfma_f32_16x16x32_bf16(aw, bx, acc[mi], 0, 0, 0);
        }
    }
    int e = wid * 16 + lrow;
#pragma unroll
    for (int mi = 0; mi < 2; ++mi)
#pragma unroll
        for (int r = 0; r < 4; ++r) {
            int m = mi * 16 + kg * 4 + r;
            xf[((size_t)(h * MODES + m) * B + b) * E + e] = make_float2(acc[mi][r], acc[mi + 2][r]);
        }
}

// ---------------- MFMA iDFT ----------------
__global__ __launch_bounds__(256) void idft_mfma(const float2* __restrict__ sel,
                                                 const unsigned short* __restrict__ twi,
                                                 unsigned short* __restrict__ out, float scale)
{
    int b = blockIdx.x / H, h = blockIdx.x % H;
    __shared__ unsigned short Ss[64][72];    // [o][m'], m' = 32 re + 32 im
    int tid = threadIdx.x;
    for (int i = tid; i < MODES * E; i += 256) {
        int m = i >> 6, o = i & 63;
        float2 v = sel[((size_t)(h * MODES + m) * B + b) * E + o];
        Ss[o][m] = f2bf_n(v.x);
        Ss[o][m + 32] = f2bf_n(v.y);
    }
    __syncthreads();
    int wid = tid >> 6, lane = tid & 63;
    int lrow = lane & 15, kg = lane >> 4;
    f32x4 acc[2][4] = {};
#pragma unroll
    for (int k0 = 0; k0 < 2; ++k0) {
        shortx8 bs[4];
#pragma unroll
        for (int ni = 0; ni < 4; ++ni)
            bs[ni] = *(const shortx8*)&Ss[ni * 16 + lrow][k0 * 32 + kg * 8];
#pragma unroll
        for (int ti = 0; ti < 2; ++ti) {
            shortx8 at = *(const shortx8*)&twi[(size_t)((wid * 2 + ti) * 16 + lrow) * 64 + k0 * 32 + kg * 8];
#pragma unroll
            for (int ni = 0; ni < 4; ++ni)
                acc[ti][ni] = __builtin_amdgcn_mfma_f32_16x16x32_bf16(at, bs[ni], acc[ti][ni], 0, 0, 0);
        }
    }
#pragma unroll
    for (int ti = 0; ti < 2; ++ti)
#pragma unroll
        for (int ni = 0; ni < 4; ++ni)
#pragma unroll
            for (int r = 0; r < 4; ++r) {
                int t = (wid * 2 + ti) * 16 + kg * 4 + r;
                if (t < L) {
                    int o = ni * 16 + lrow;
                    out[((size_t)b * L + t) * D + h * E + o] = f2bf_n(acc[ti][ni][r] * scale);
                }
            }
}

// ---------------- per-(h,m) complex GEMM, in place ----------------
__global__ __launch_bounds__(256) void mode_gemm2(float2* __restrict__ xf, const float2* __restrict__ wt)
{
    int hm = blockIdx.x;
    int bt = blockIdx.y;
    __shared__ float2 Wc[E][E];
    __shared__ float2 Ac[32][E];
    for (int i = threadIdx.x; i < E * E; i += 256) Wc[i / E][i % E] = wt[(size_t)hm * (E * E) + i];
    for (int i = threadIdx.x; i < 32 * E; i += 256)
        Ac[i / E][i % E] = xf[((size_t)hm * B + bt * 32 + i / E) * E + i % E];
    __syncthreads();
    int o = threadIdx.x & 63, bb = threadIdx.x >> 6;
    float2 acc[8];
#pragma unroll
    for (int j = 0; j < 8; ++j) acc[j] = make_float2(0.f, 0.f);
    for (int e = 0; e < E; ++e) {
        float2 w = Wc[e][o];
#pragma unroll
        for (int j = 0; j < 8; ++j) {
            float2 a = Ac[bb * 8 + j][e];
            acc[j].x += a.x * w.x - a.y * w.y;
            acc[j].y += a.x * w.y + a.y * w.x;
        }
    }
#pragma unroll
    for (int j = 0; j < 8; ++j)
        xf[((size_t)hm * B + bt * 32 + bb * 8 + j) * E + o] = acc[j];
}

// FourierCross steps 1-2 (fp32 freq domain)
__global__ __launch_bounds__(256) void fourier_qk(const float2* __restrict__ qf, float2* __restrict__ kf)
{
    int b = blockIdx.x / H, h = blockIdx.x % H;
    __shared__ float2 qm[MODES][E + 1], km[MODES][E + 1], vm[MODES][E + 1];
    __shared__ float tr[MODES][MODES + 1], ti[MODES][MODES + 1];
    for (int i = threadIdx.x; i < MODES * E; i += 256) {
        int m = i / E, e = i % E;
        size_t idx = ((size_t)(h * MODES + m) * B + b) * E + e;
        qm[m][e] = qf[idx];
        km[m][e] = kf[idx];
    }
    __syncthreads();
    for (int i = threadIdx.x; i < MODES * MODES; i += 256) {
        int x = i / MODES, y = i % MODES;
        float re = 0.f, im = 0.f;
        for (int e = 0; e < E; ++e) {
            float2 a = qm[x][e], k2 = km[y][e];
            re += a.x * k2.x - a.y * k2.y;
            im += a.x * k2.y + a.y * k2.x;
        }
        float aa = fminf(fmaxf(2.f * re, -30.f), 30.f);
        float b2 = 2.f * im;
        float den = coshf(aa) + cosf(b2);
        tr[x][y] = sinhf(aa) / den;
        ti[x][y] = sinf(b2) / den;
    }
    __syncthreads();
    for (int i = threadIdx.x; i < MODES * E; i += 256) {
        int x = i / E, e = i % E;
        float re = 0.f, im = 0.f;
        for (int y = 0; y < MODES; ++y) {
            float ar = tr[x][y], ai = ti[x][y];
            float2 kk = km[y][e];
            re += ar * kk.x - ai * kk.y;
            im += ar * kk.y + ai * kk.x;
        }
        vm[x][e] = make_float2(re, im);
    }
    __syncthreads();
    for (int i = threadIdx.x; i < MODES * E; i += 256) {
        int m = i / E, e = i % E;
        kf[((size_t)(h * MODES + m) * B + b) * E + e] = vm[m][e];
    }
}

// sigma + prior fused
__global__ __launch_bounds__(256) void sigma_prior(const unsigned short* __restrict__ enc,
                                                   const float* __restrict__ w,
                                                   const float* __restrict__ bias,
                                                   float* __restrict__ sig_out, float* __restrict__ prior)
{
    __shared__ float wsh[H][D];
    for (int i = threadIdx.x; i < H * D; i += 256) wsh[i / D][i % D] = w[i];
    __syncthreads();
    int wid = threadIdx.x / 64, lane = threadIdx.x % 64;
    int row = blockIdx.x * 4 + wid;
    const unsigned short* p = enc + (size_t)row * D;
    float xv[8];
#pragma unroll
    for (int i = 0; i < 8; ++i) xv[i] = bf2f(p[lane + i * 64]);
    int b = row / L, l = row % L;
#pragma unroll
    for (int h = 0; h < H; ++h) {
        float s = 0.f;
#pragma unroll
        for (int i = 0; i < 8; ++i) s += xv[i] * wsh[h][lane + i * 64];
        for (int off = 32; off; off >>= 1) s += __shfl_xor(s, off);
        float acc = s + bias[h];
        float sg = 1.f / (1.f + expf(-5.f * acc));
        float val = expf((sg + 1e-5f) * 1.0986122886681098f) - 1.f; // 3^u - 1
        if (lane == 0) sig_out[((size_t)b * H + h) * L + l] = val;
        float inv2 = 1.f / (2.f * val * val);
        float coef = INV_SQRT_2PI / val;
        float* pr = prior + (((size_t)b * H + h) * L + l) * L;
        for (int sc = lane; sc < L; sc += 64) {
            float d = (float)abs(l - sc);
            pr[sc] = expf(-d * d * inv2) * coef;
        }
    }
}

// series_decomp_multi via replicate-padded prefix sum
__global__ __launch_bounds__(256) void decomp_kernel(const unsigned short* __restrict__ in1,
                                                     const unsigned short* __restrict__ in2,
                                                     const float* __restrict__ w, const float* __restrict__ bc,
                                                     unsigned short* __restrict__ res, float* __restrict__ trend,
                                                     unsigned short* __restrict__ trend16, int tmode)
{
    int b = blockIdx.x / (D / 64);
    int d0 = (blockIdx.x % (D / 64)) * 64;
    __shared__ float P[125][65];
    __shared__ float qtot[4][64];
    int tid = threadIdx.x;
    int dd = tid & 63, q = tid >> 6;
    int p0 = q * 31;
    float run = 0.f;
#pragma unroll
    for (int i = 0; i < 31; ++i) {
        int p = p0 + i;
        int j = min(max(p - 12, 0), L - 1);
        size_t g = ((size_t)b * L + j) * D + d0 + dd;
        float v = bf2f(in1[g]);
        if (in2) v += bf2f(in2[g]);
        run += v;
        P[p + 1][dd] = run;
    }
    qtot[q][dd] = run;
    if (tid < 64) P[0][dd] = 0.f;
    __syncthreads();
    if (q > 0) {
        float off = qtot[0][dd];
        if (q > 1) off += qtot[1][dd];
        if (q > 2) off += qtot[2][dd];
#pragma unroll
        for (int i = 0; i < 31; ++i)
            P[p0 + i + 1][dd] += off;
    }
    __syncthreads();
    float w0 = w[0], w1 = w[1], b0 = bc[0], b1 = bc[1];
    for (int i = tid; i < L * 64; i += 256) {
        int l = i >> 6, d2 = i & 63;
        float s12 = P[l + 19][d2] - P[l + 7][d2];
        float s24 = P[l + 25][d2] - P[l + 1][d2];
        float x = P[l + 13][d2] - P[l + 12][d2];
        float m0 = s12 * (1.f / 12.f), m1 = s24 * (1.f / 24.f);
        float z0 = x * w0 + b0, z1 = x * w1 + b1;
        float zm = fmaxf(z0, z1);
        float e0 = expf(z0 - zm), e1 = expf(z1 - zm);
        float p0f = e0 / (e0 + e1);
        float mean = m0 * p0f + m1 * (1.f - p0f);
        size_t g = ((size_t)b * L + l) * D + d0 + d2;
        res[g] = f2bf_n(x - mean);
        if (tmode == 1) trend[g] = mean;
        else if (tmode == 2) {
            float tv = trend[g] + mean;
            trend[g] = tv;
            if (trend16) trend16[g] = f2bf_n(tv);
        }
    }
}

// fused my_layernorm: per-row LN then per-column mean subtract; one block per batch b.
__global__ __launch_bounds__(256) void ln_colsub(const unsigned short* __restrict__ x,
                                                 const float* __restrict__ g, const float* __restrict__ bb,
                                                 unsigned short* __restrict__ out)
{
    int b = blockIdx.x;
    __shared__ unsigned short xs[L][D];      // 100*512*2 = 102,400 B
    __shared__ float colmean[D];
    __shared__ float gs[D], bs2[D];
    int tid = threadIdx.x;
    for (int i = tid; i < L * D / 8; i += 256) {
        int l = i / 64, c8 = (i % 64) * 8;
        *(shortx8*)&xs[l][c8] = *(const shortx8*)&x[((size_t)b * L + l) * D + c8];
    }
    for (int i = tid; i < D; i += 256) { gs[i] = g[i]; bs2[i] = bb[i]; }
    __syncthreads();
    int wid = tid >> 6, lane = tid & 63;
    for (int l = wid; l < L; l += 4) {
        float v[8];
        float s = 0.f, s2 = 0.f;
#pragma unroll
        for (int i = 0; i < 8; ++i) {
            v[i] = bf2f(xs[l][lane + i * 64]);
            s += v[i]; s2 += v[i] * v[i];
        }
        for (int off = 32; off; off >>= 1) { s += __shfl_xor(s, off); s2 += __shfl_xor(s2, off); }
        float mu = s / (float)D;
        float var = s2 / (float)D - mu * mu;
        float rstd = rsqrtf(var + 1e-5f);
#pragma unroll
        for (int i = 0; i < 8; ++i) {
            int d = lane + i * 64;
            xs[l][d] = f2bf_n((v[i] - mu) * rstd * gs[d] + bs2[d]);
        }
    }
    __syncthreads();
    for (int c = tid; c < D; c += 256) {
        float s = 0.f;
        for (int l = 0; l < L; ++l) s += bf2f(xs[l][c]);
        colmean[c] = s * (1.f / (float)L);
    }
    __syncthreads();
    for (int i = tid; i < L * D; i += 256) {
        int l = i / D, c = i % D;
        out[((size_t)b * L + l) * D + c] = f2bf_n(bf2f(xs[l][c]) - colmean[c]);
    }
}

extern "C" void kernel_launch(void* const* d_in, const int* in_sizes, int n_in,
                              void* d_out, int out_size, void* d_ws, size_t ws_size,
                              hipStream_t stream)
{
    const float* x           = (const float*)d_in[0];
    const float* emb_enc_w   = (const float*)d_in[1];
    const float* emb_dec_w   = (const float*)d_in[2];
    const float* enc_proj_w  = (const float*)d_in[3];
    const float* enc_proj_b  = (const float*)d_in[4];
    const float* enc_sig_w   = (const float*)d_in[5];
    const float* enc_sig_b   = (const float*)d_in[6];
    const float* enc_four_wr = (const float*)d_in[7];
    const float* enc_four_wi = (const float*)d_in[8];
    const float* enc_ffn_w1  = (const float*)d_in[9];
    const float* enc_ffn_w2  = (const float*)d_in[10];
    const float* enc_dcmp_w  = (const float*)d_in[11];
    const float* enc_dcmp_b  = (const float*)d_in[12];
    const float* enc_norm_g  = (const float*)d_in[13];
    const float* enc_norm_b  = (const float*)d_in[14];
    const float* dec_proj_w  = (const float*)d_in[15];
    const float* dec_proj_b  = (const float*)d_in[16];
    const float* dec_four_wr = (const float*)d_in[17];
    const float* dec_four_wi = (const float*)d_in[18];
    const float* crs_proj_w  = (const float*)d_in[19];
    const float* crs_proj_b  = (const float*)d_in[20];
    const float* crs_four_wr = (const float*)d_in[21];
    const float* crs_four_wi = (const float*)d_in[22];
    const float* dec_ffn_w1  = (const float*)d_in[23];
    const float* dec_ffn_w2  = (const float*)d_in[24];
    const float* dec_dcmp_w  = (const float*)d_in[25];
    const float* dec_dcmp_b  = (const float*)d_in[26];
    const float* dec_trend_w = (const float*)d_in[27];
    const float* dec_norm_g  = (const float*)d_in[28];
    const float* dec_norm_b  = (const float*)d_in[29];
    const float* out_proj_w  = (const float*)d_in[30];
    const float* out_proj_b  = (const float*)d_in[31];

    float* ws = (float*)d_ws;
    size_t off = 0;
    float* pe    = ws + off; off += (size_t)L * D;
    float* xmean = ws + off; off += (size_t)B * CIN;
    float* bufF  = ws + off; off += BLD;           // fp32 scratch (trend Y)
    float* tacc  = ws + off; off += BLD;           // fp32 trend accumulator
    float2* xfc  = (float2*)(ws + off); off += 2 * BHEM;
    float2* kfc  = (float2*)(ws + off); off += 2 * BHEM;
    float2* wtb  = (float2*)(ws + off); off += 2 * (size_t)H * MODES * E * E;
    // bf16 activation buffers
    unsigned short* qk16 = (unsigned short*)(ws + off); off += BLD;        // 2*BLD shorts (q|k fused, stride 1024)
    unsigned short* e16  = (unsigned short*)(ws + off); off += BLD / 2;
    unsigned short* c16  = (unsigned short*)(ws + off); off += BLD / 2;
    unsigned short* d16  = (unsigned short*)(ws + off); off += BLD / 2;
    unsigned short* h16  = (unsigned short*)(ws + off); off += BLD / 2;
    unsigned short* t16  = (unsigned short*)(ws + off); off += BLD / 2;
    unsigned short* im16 = (unsigned short*)(ws + off); off += (size_t)M_ROWS * KEMB / 2;
    // bf16 weights + twiddle tables
    unsigned short* wbf_encproj = (unsigned short*)(ws + off); off += (size_t)2 * 4 * D * D / 2;
    unsigned short* wbf_ffn1    = (unsigned short*)(ws + off); off += (size_t)2 * DFF * D / 2;
    unsigned short* wbf_ffn2    = (unsigned short*)(ws + off); off += (size_t)2 * D * DFF / 2;
    unsigned short* wbf_decproj = (unsigned short*)(ws + off); off += (size_t)4 * D * D / 2;
    unsigned short* wbf_crsproj = (unsigned short*)(ws + off); off += (size_t)4 * D * D / 2;
    unsigned short* wbf_dffn1   = (unsigned short*)(ws + off); off += (size_t)DFF * D / 2;
    unsigned short* wbf_dffn2   = (unsigned short*)(ws + off); off += (size_t)D * DFF / 2;
    unsigned short* wbf_embenc  = (unsigned short*)(ws + off); off += (size_t)D * KEMB / 2;
    unsigned short* wbf_embdec  = (unsigned short*)(ws + off); off += (size_t)D * KEMB / 2;
    unsigned short* wbf_trd     = (unsigned short*)(ws + off); off += (size_t)192 * D / 2;
    unsigned short* wbf_seas    = (unsigned short*)(ws + off); off += (size_t)64 * D / 2;
    unsigned short* twf         = (unsigned short*)(ws + off); off += (size_t)64 * 128 / 2;
    unsigned short* twi         = (unsigned short*)(ws + off); off += (size_t)128 * 64 / 2;
    unsigned short* a16 = qk16;               // decoder reuse of qk region
    unsigned short* b16 = qk16 + BLD;

    float* out       = (float*)d_out;
    float* dec_out   = out;
    float* series_out= out + (size_t)B * L * COUT;
    float* prior_out = series_out + 2 * BHLL;
    float* sigma_out = prior_out + 2 * BHLL;

    const int BH = B * H;

    init_consts<<<200, 256, 0, stream>>>(pe);
    init_tw<<<32, 256, 0, stream>>>(twf, twi);
    xmean_kernel<<<cdiv(B * CIN, 256), 256, 0, stream>>>(x, xmean);

    // merged weight prep (7 bulk bf16 conversions + 4 padded layouts) in ONE launch
    PrepArgs pa;
    pa.src[0] = enc_proj_w; pa.dst[0] = wbf_encproj; pa.n4[0] = 2 * 4 * D * D / 4;
    pa.src[1] = enc_ffn_w1; pa.dst[1] = wbf_ffn1;    pa.n4[1] = 2 * DFF * D / 4;
    pa.src[2] = enc_ffn_w2; pa.dst[2] = wbf_ffn2;    pa.n4[2] = 2 * D * DFF / 4;
    pa.src[3] = dec_proj_w; pa.dst[3] = wbf_decproj; pa.n4[3] = 4 * D * D / 4;
    pa.src[4] = crs_proj_w; pa.dst[4] = wbf_crsproj; pa.n4[4] = 4 * D * D / 4;
    pa.src[5] = dec_ffn_w1; pa.dst[5] = wbf_dffn1;   pa.n4[5] = DFF * D / 4;
    pa.src[6] = dec_ffn_w2; pa.dst[6] = wbf_dffn2;   pa.n4[6] = D * DFF / 4;
    pa.emb_enc = emb_enc_w; pa.emb_dec = emb_dec_w; pa.trend_w = dec_trend_w; pa.seas_w = out_proj_w;
    pa.d_embenc = wbf_embenc; pa.d_embdec = wbf_embdec; pa.d_trd = wbf_trd; pa.d_seas = wbf_seas;
    int total4 = 0;
    for (int s = 0; s < 7; ++s) total4 += pa.n4[s];
    int padTotal = 2 * D * KEMB + 192 * D + 64 * D;
    prep_all<<<2048, 256, 0, stream>>>(pa, total4, padTotal);
    transpose_w<<<H * E, 256, 0, stream>>>(enc_four_wr, enc_four_wi, wtb);

    auto gemm = [&](const unsigned short* A, const unsigned short* Wb, const float* bias, const float* pe_,
                    const unsigned short* resid, float* C, unsigned short* Cb,
                    int N, int Nout, int K, int act, int accum) {
        if (N % 128 == 0) {
            dim3 grid(N / 128, M_ROWS / 128);
            gemm_mfma<128><<<grid, 256, 0, stream>>>(A, Wb, bias, pe_, resid, C, Cb, Nout, K, act, accum);
        } else {
            dim3 grid(N / 64, M_ROWS / 128);
            gemm_mfma<64><<<grid, 256, 0, stream>>>(A, Wb, bias, pe_, resid, C, Cb, Nout, K, act, accum);
        }
    };
    dim3 mg_grid(H * MODES, B / 32);
    dim3 sc_grid(BH, 2);

    // encoder embedding
    im2col_emb<<<cdiv(M_ROWS * KEMB, 256), 256, 0, stream>>>(x, nullptr, im16);
    gemm(im16, wbf_embenc, nullptr, pe, nullptr, nullptr, e16, D, D, KEMB, 0, 0);

    for (int i = 0; i < 2; ++i) {
        const unsigned short* Wp = wbf_encproj + (size_t)i * 4 * D * D;
        const float* bp = enc_proj_b + (size_t)i * 4 * D;
        float* series_i = series_out + (size_t)i * BHLL;
        float* prior_i  = prior_out  + (size_t)i * BHLL;
        float* sigma_i  = sigma_out  + (size_t)i * B * H * L;

        gemm(e16, Wp, bp, nullptr, nullptr, nullptr, qk16, 1024, 1024, D, 0, 0);       // fused q+k
        dft_mfma<<<BH, 256, 0, stream>>>(qk16, twf, xfc, 1024);
        mode_gemm2<<<mg_grid, 256, 0, stream>>>(xfc, wtb);
        idft_mfma<<<BH, 256, 0, stream>>>(xfc, twi, c16, 1.f / (float)L);
        // attn_out + residual(e16) fused into epilogue
        gemm(c16, Wp + (size_t)3 * D * D, bp + 3 * D, nullptr, e16, nullptr, d16, D, D, D, 0, 0);
        scores_softmax<<<sc_grid, 256, 0, stream>>>(qk16, series_i);
        sigma_prior<<<M_ROWS / 4, 256, 0, stream>>>(e16, enc_sig_w + (size_t)i * H * D,
                                                    enc_sig_b + (size_t)i * H, sigma_i, prior_i);
        decomp_kernel<<<B * (D / 64), 256, 0, stream>>>(d16, nullptr, enc_dcmp_w + (size_t)(i * 2 + 0) * NK,
                                                        enc_dcmp_b + (size_t)(i * 2 + 0) * NK, h16, nullptr, nullptr, 0);
        gemm(h16, wbf_ffn1 + (size_t)i * DFF * D, nullptr, nullptr, nullptr, nullptr, c16, DFF, DFF, D, 1, 0);
        // ffn2 + residual(h16) fused
        gemm(c16, wbf_ffn2 + (size_t)i * D * DFF, nullptr, nullptr, h16, nullptr, d16, D, D, DFF, 0, 0);
        decomp_kernel<<<B * (D / 64), 256, 0, stream>>>(d16, nullptr, enc_dcmp_w + (size_t)(i * 2 + 1) * NK,
                                                        enc_dcmp_b + (size_t)(i * 2 + 1) * NK, e16, nullptr, nullptr, 0);
    }
    // encoder final my_layernorm (fused LN + column-mean subtract), in place on e16
    ln_colsub<<<B, 256, 0, stream>>>(e16, enc_norm_g, enc_norm_b, e16);

    // ---------------- decoder ----------------
    transpose_w<<<H * E, 256, 0, stream>>>(dec_four_wr, dec_four_wi, wtb);
    im2col_emb<<<cdiv(M_ROWS * KEMB, 256), 256, 0, stream>>>(x, xmean, im16);
    gemm(im16, wbf_embdec, nullptr, pe, nullptr, nullptr, a16, D, D, KEMB, 0, 0);          // dec
    gemm(a16, wbf_decproj, dec_proj_b, nullptr, nullptr, nullptr, b16, D, D, D, 0, 0);     // q
    dft_mfma<<<BH, 256, 0, stream>>>(b16, twf, xfc, D);
    mode_gemm2<<<mg_grid, 256, 0, stream>>>(xfc, wtb);
    idft_mfma<<<BH, 256, 0, stream>>>(xfc, twi, c16, 1.f / (float)L);
    // sa + residual(a16) fused
    gemm(c16, wbf_decproj + (size_t)3 * D * D, dec_proj_b + 3 * D, nullptr, a16, nullptr, d16, D, D, D, 0, 0);
    decomp_kernel<<<B * (D / 64), 256, 0, stream>>>(d16, nullptr, dec_dcmp_w, dec_dcmp_b, h16, tacc, nullptr, 1); // h, t1

    gemm(h16, wbf_crsproj, crs_proj_b, nullptr, nullptr, nullptr, b16, D, D, D, 0, 0);     // qc
    dft_mfma<<<BH, 256, 0, stream>>>(b16, twf, xfc, D);                                    // qf
    gemm(e16, wbf_crsproj + (size_t)D * D, crs_proj_b + D, nullptr, nullptr, nullptr, b16, D, D, D, 0, 0); // kc
    dft_mfma<<<BH, 256, 0, stream>>>(b16, twf, kfc, D);                                    // kf
    transpose_w<<<H * E, 256, 0, stream>>>(crs_four_wr, crs_four_wi, wtb);
    fourier_qk<<<BH, 256, 0, stream>>>(xfc, kfc);                                          // kfc := qkv
    mode_gemm2<<<mg_grid, 256, 0, stream>>>(kfc, wtb);
    idft_mfma<<<BH, 256, 0, stream>>>(kfc, twi, c16, 1.f / ((float)L * (float)D * (float)D));
    // ca + residual(h16) fused
    gemm(c16, wbf_crsproj + (size_t)3 * D * D, crs_proj_b + 3 * D, nullptr, h16, nullptr, d16, D, D, D, 0, 0);
    decomp_kernel<<<B * (D / 64), 256, 0, stream>>>(d16, nullptr, dec_dcmp_w + NK, dec_dcmp_b + NK, a16, tacc, nullptr, 2); // h2, t2

    gemm(a16, wbf_dffn1, nullptr, nullptr, nullptr, nullptr, c16, DFF, DFF, D, 1, 0);
    // dffn2 + residual(a16) fused
    gemm(c16, wbf_dffn2, nullptr, nullptr, a16, nullptr, d16, D, D, DFF, 0, 0);
    decomp_kernel<<<B * (D / 64), 256, 0, stream>>>(d16, nullptr, dec_dcmp_w + 2 * NK, dec_dcmp_b + 2 * NK, b16, tacc, t16, 2); // h3, t3 (+bf16 trend)

    // trend conv: stacked-tap GEMM (K=512, N=192, fp32 out) -> combine with trend_init (xmean)
    gemm(t16, wbf_trd, nullptr, nullptr, nullptr, bufF, nullptr, 192, 192, D, 0, 0);
    trend_combine<<<cdiv(B * L * COUT, 256), 256, 0, stream>>>(bufF, xmean, dec_out);

    // final layernorm (fused) + seasonal projection accumulated into dec_out
    ln_colsub<<<B, 256, 0, stream>>>(b16, dec_norm_g, dec_norm_b, d16);
    gemm(d16, wbf_seas, out_proj_b, nullptr, nullptr, dec_out, nullptr, 64, COUT, D, 0, 1);
}

// Round 15
// 1184.891 us; speedup vs baseline: 1.1286x; 1.1286x over previous
//
#include <hip/hip_runtime.h>
#include <hip/hip_bf16.h>
#include <cmath>

constexpr int B = 128, L = 100, CIN = 55, COUT = 55;
constexpr int D = 512, H = 8, DFF = 512, MODES = 32, E = 64;
constexpr int NK = 2;
constexpr int M_ROWS = B * L; // 12800
constexpr int KEMB = 192;     // 55*3=165 padded to 32*6
constexpr size_t BLD  = (size_t)B * L * D;         // 6,553,600
constexpr size_t BHEM = (size_t)B * H * E * MODES; // 2,097,152 complex elems
constexpr size_t BHLL = (size_t)B * H * L * L;     // 10,240,000
constexpr float INV_SQRT_2PI = 0.3989422804014327f;

static inline int cdiv(int a, int b) { return (a + b - 1) / b; }

typedef short shortx8 __attribute__((ext_vector_type(8)));
typedef float f32x4 __attribute__((ext_vector_type(4)));

__device__ inline unsigned short f2bf(float f)    // RNE (weight prep)
{
    unsigned int u = __float_as_uint(f);
    unsigned int r = (u + 0x7FFFu + ((u >> 16) & 1u)) >> 16;
    return (unsigned short)r;
}
__device__ inline unsigned short f2bf_n(float f)  // native cvt
{
    union { __hip_bfloat16 h; unsigned short u; } cv;
    cv.h = __float2bfloat16(f);
    return cv.u;
}
__device__ inline float bf2f(unsigned short u)
{
    union { unsigned int i; float f; } c;
    c.i = (unsigned int)u << 16;
    return c.f;
}

// ---------------- constants ----------------
__global__ void init_consts(float* __restrict__ pe)
{
    int idx = blockIdx.x * 256 + threadIdx.x;
    if (idx < L * D) {
        int l = idx / D, d = idx % D;
        int i2 = d & ~1;
        float div = expf((float)i2 * (-logf(10000.f) / (float)D));
        float ang = (float)l * div;
        pe[idx] = (d & 1) ? cosf(ang) : sinf(ang);
    }
}

// bf16 twiddle tables for MFMA DFT/iDFT
__global__ void init_tw(unsigned short* __restrict__ twf, unsigned short* __restrict__ twi)
{
    int idx = blockIdx.x * 256 + threadIdx.x;
    if (idx >= 64 * 128) return;
    {
        int mp = idx / 128, t = idx % 128;
        float v = 0.f;
        if (t < L) {
            if (mp < 32) v = cosf(2.f * 3.14159265358979323846f * (float)mp * (float)t / (float)L);
            else v = -sinf(2.f * 3.14159265358979323846f * (float)(mp - 32) * (float)t / (float)L);
        }
        twf[idx] = f2bf(v);
    }
    {
        int t = idx / 64, mp = idx % 64;
        float v = 0.f;
        if (t < L) {
            if (mp == 0) v = 1.f;
            else if (mp < 32) v = 2.f * cosf(2.f * 3.14159265358979323846f * (float)mp * (float)t / (float)L);
            else if (mp == 32) v = 0.f;
            else v = -2.f * sinf(2.f * 3.14159265358979323846f * (float)(mp - 32) * (float)t / (float)L);
        }
        twi[idx] = f2bf(v);
    }
}

__global__ void xmean_kernel(const float* __restrict__ x, float* __restrict__ xm)
{
    int idx = blockIdx.x * 256 + threadIdx.x;
    if (idx >= B * CIN) return;
    int b = idx / CIN, c = idx % CIN;
    float s = 0.f;
    for (int l = 0; l < L; ++l) s += x[((size_t)b * L + l) * CIN + c];
    xm[idx] = s * (1.f / (float)L);
}

// ---------------- single merged weight-prep kernel ----------------
struct PrepArgs {
    const float* src[7];
    unsigned short* dst[7];
    int n4[7];               // float4 count per segment
    const float* emb_enc; const float* emb_dec; const float* trend_w; const float* seas_w;
    unsigned short* d_embenc; unsigned short* d_embdec; unsigned short* d_trd; unsigned short* d_seas;
};
__global__ __launch_bounds__(256) void prep_all(PrepArgs a, int total4, int padTotal)
{
    for (int i = blockIdx.x * 256 + threadIdx.x; i < total4 + padTotal; i += gridDim.x * 256) {
        if (i < total4) {
            int idx = i, s = 0;
            while (idx >= a.n4[s]) { idx -= a.n4[s]; ++s; }
            float4 v = *(const float4*)&a.src[s][(size_t)idx * 4];
            ushort4 h;
            h.x = f2bf(v.x); h.y = f2bf(v.y); h.z = f2bf(v.z); h.w = f2bf(v.w);
            *(ushort4*)&a.dst[s][(size_t)idx * 4] = h;
            continue;
        }
        int p = i - total4;
        if (p < D * KEMB) {
            int r = p / KEMB, k = p % KEMB;
            a.d_embenc[p] = (k < CIN * 3) ? f2bf(a.emb_enc[(size_t)r * (CIN * 3) + k]) : (unsigned short)0;
        } else if ((p -= D * KEMB) < D * KEMB) {
            int r = p / KEMB, k = p % KEMB;
            a.d_embdec[p] = (k < CIN * 3) ? f2bf(a.emb_dec[(size_t)r * (CIN * 3) + k]) : (unsigned short)0;
        } else if ((p -= D * KEMB) < 192 * D) {
            int n = p / D, d = p % D;
            int j = n / 64, o = n % 64;
            a.d_trd[p] = (o < COUT) ? f2bf(a.trend_w[(size_t)o * (D * 3) + d * 3 + j]) : (unsigned short)0;
        } else {
            p -= 192 * D;
            int r = p / D, k = p % D;
            a.d_seas[p] = (r < COUT) ? f2bf(a.seas_w[(size_t)r * D + k]) : (unsigned short)0;
        }
    }
}

// Fourier weight transpose -> bf16 [hm][{re,im}][o][e]; one block per (h,o)
__global__ __launch_bounds__(256) void transpose_wb(const float* __restrict__ wr, const float* __restrict__ wi,
                                                    unsigned short* __restrict__ wt)
{
    int h = blockIdx.x / E, o = blockIdx.x % E;
    __shared__ float tr[64][33], ti[64][33];
    for (int i = threadIdx.x; i < E * MODES; i += 256) {
        int e = i >> 5, m = i & 31;
        size_t s = (((size_t)h * E + e) * E + o) * MODES + m;
        tr[e][m] = wr[s]; ti[e][m] = wi[s];
    }
    __syncthreads();
    for (int i = threadIdx.x; i < MODES * E; i += 256) {
        int m = i >> 6, e = i & 63;
        size_t base = ((size_t)(h * MODES + m) * 2) * 4096 + (size_t)o * 64 + e;
        wt[base] = f2bf(tr[e][m]);
        wt[base + 4096] = f2bf(ti[e][m]);
    }
}

// im2col for kernel-3 circular conv: bf16 out
__global__ void im2col_emb(const float* __restrict__ x, const float* __restrict__ xmean,
                           unsigned short* __restrict__ A2)
{
    int idx = blockIdx.x * 256 + threadIdx.x;
    if (idx >= M_ROWS * KEMB) return;
    int k = idx % KEMB, m = idx / KEMB;
    float v = 0.f;
    if (k < CIN * 3) {
        int c = k / 3, j = k % 3;
        int l = m % L, b = m / L;
        int ls = l + j - 1; ls = (ls + L) % L;
        v = x[((size_t)b * L + ls) * CIN + c];
        if (xmean) v -= xmean[(size_t)b * CIN + c];
    }
    A2[idx] = f2bf(v);
}

// ---------------- bf16 MFMA GEMM, double-buffered LDS, ONE barrier per K-step ----------------
template<int BN>
__global__ __launch_bounds__(256) void gemm_mfma(const unsigned short* __restrict__ A,
                                                 const unsigned short* __restrict__ Wb,
                                                 const float* __restrict__ bias, const float* __restrict__ pe,
                                                 float* __restrict__ C, unsigned short* __restrict__ Cb,
                                                 int Nout, int K, int act, int accum)
{
    constexpr int NI = BN / 32;
    constexpr int BI = BN / 64;
    __shared__ unsigned short As[2][128][40];
    __shared__ unsigned short Bs[2][BN][40];
    int tid = threadIdx.x;
    int row0 = blockIdx.y * 128, col0 = blockIdx.x * BN;
    int wid = tid >> 6, lane = tid & 63;
    int wm = wid >> 1, wn = wid & 1;
    int lrow = lane & 15, kg = lane >> 4;
    int ar = tid >> 2, ac8 = (tid & 3) * 8;
    f32x4 acc[4][NI] = {};
    shortx8 rah[2], rbh[BI];

    auto loadG = [&](int k0) {
#pragma unroll
        for (int p = 0; p < 2; ++p)
            rah[p] = *(const shortx8*)&A[(size_t)(row0 + p * 64 + ar) * K + k0 + ac8];
#pragma unroll
        for (int p = 0; p < BI; ++p)
            rbh[p] = *(const shortx8*)&Wb[(size_t)(col0 + p * 64 + ar) * K + k0 + ac8];
    };
    auto storeLDS = [&](int buf) {
#pragma unroll
        for (int p = 0; p < 2; ++p)
            *(shortx8*)&As[buf][p * 64 + ar][ac8] = rah[p];
#pragma unroll
        for (int p = 0; p < BI; ++p)
            *(shortx8*)&Bs[buf][p * 64 + ar][ac8] = rbh[p];
    };

    int nk = K >> 5;
    loadG(0);
    storeLDS(0);
    if (nk > 1) loadG(32);
    __syncthreads();
    int cur = 0;
    for (int s = 0; s < nk; ++s) {
        if (s + 1 < nk) {
            storeLDS(cur ^ 1);                 // tile s+1 (regs) -> other buffer
            if (s + 2 < nk) loadG((s + 2) << 5); // issue loads for tile s+2
        }
        shortx8 av[4], bv[NI];
#pragma unroll
        for (int mi = 0; mi < 4; ++mi)
            av[mi] = *(const shortx8*)&As[cur][wm * 64 + mi * 16 + lrow][kg * 8];
#pragma unroll
        for (int ni = 0; ni < NI; ++ni)
            bv[ni] = *(const shortx8*)&Bs[cur][wn * (BN / 2) + ni * 16 + lrow][kg * 8];
#pragma unroll
        for (int mi = 0; mi < 4; ++mi)
#pragma unroll
            for (int ni = 0; ni < NI; ++ni)
                acc[mi][ni] = __builtin_amdgcn_mfma_f32_16x16x32_bf16(av[mi], bv[ni], acc[mi][ni], 0, 0, 0);
        if (s + 1 < nk) __syncthreads();
        cur ^= 1;
    }
#pragma unroll
    for (int mi = 0; mi < 4; ++mi) {
#pragma unroll
        for (int ni = 0; ni < NI; ++ni) {
            int col = col0 + wn * (BN / 2) + ni * 16 + lrow;
            if (col >= Nout) continue;
#pragma unroll
            for (int r = 0; r < 4; ++r) {
                int row = row0 + wm * 64 + mi * 16 + kg * 4 + r;
                float v = acc[mi][ni][r];
                if (bias) v += bias[col];
                if (pe) v += pe[(size_t)(row % L) * Nout + col];
                if (act) v = 0.5f * v * (1.f + erff(v * 0.70710678118654752f));
                size_t o = (size_t)row * Nout + col;
                if (Cb) Cb[o] = f2bf_n(v);
                else if (accum) C[o] += v;
                else C[o] = v;
            }
        }
    }
}

// ---------------- fused QK^T/8 + row-softmax (bf16 input, row stride 1024) ----------------
__global__ __launch_bounds__(256) void scores_softmax(const unsigned short* __restrict__ QK,
                                                      float* __restrict__ out)
{
    int bh = blockIdx.x, b = bh / H, h = bh % H;
    int pass = blockIdx.y;
    __shared__ unsigned short Ks[112][72];
    __shared__ unsigned short Qs[64][72];
    int tid = threadIdx.x;
    int srow = tid >> 4, sc4 = (tid & 15) * 4;
#pragma unroll
    for (int i = 0; i < 7; ++i) {
        int r = i * 16 + srow;
        ushort4 hh = {0, 0, 0, 0};
        if (r < L) hh = *(const ushort4*)&QK[((size_t)b * L + r) * 1024 + 512 + h * E + sc4];
        *(ushort4*)&Ks[r][sc4] = hh;
    }
#pragma unroll
    for (int i = 0; i < 4; ++i) {
        int r = i * 16 + srow;
        int gr = pass * 64 + r;
        ushort4 hh = {0, 0, 0, 0};
        if (gr < L) hh = *(const ushort4*)&QK[((size_t)b * L + gr) * 1024 + h * E + sc4];
        *(ushort4*)&Qs[r][sc4] = hh;
    }
    __syncthreads();
    int wid = tid >> 6, lane = tid & 63;
    int lrow = lane & 15, kg = lane >> 4;
    f32x4 acc[7] = {};
#pragma unroll
    for (int ks = 0; ks < 2; ++ks) {
        shortx8 aq = *(const shortx8*)&Qs[wid * 16 + lrow][ks * 32 + kg * 8];
#pragma unroll
        for (int tj = 0; tj < 7; ++tj) {
            shortx8 bk = *(const shortx8*)&Ks[tj * 16 + lrow][ks * 32 + kg * 8];
            acc[tj] = __builtin_amdgcn_mfma_f32_16x16x32_bf16(aq, bk, acc[tj], 0, 0, 0);
        }
    }
    float mx[4] = {-1e30f, -1e30f, -1e30f, -1e30f};
#pragma unroll
    for (int tj = 0; tj < 7; ++tj) {
        bool valid = (tj * 16 + lrow) < L;
#pragma unroll
        for (int r = 0; r < 4; ++r) {
            float v = acc[tj][r] * 0.125f;
            acc[tj][r] = valid ? v : -1e30f;
            if (valid) mx[r] = fmaxf(mx[r], v);
        }
    }
#pragma unroll
    for (int off = 1; off < 16; off <<= 1)
#pragma unroll
        for (int r = 0; r < 4; ++r) mx[r] = fmaxf(mx[r], __shfl_xor(mx[r], off));
    float sum[4] = {0.f, 0.f, 0.f, 0.f};
#pragma unroll
    for (int tj = 0; tj < 7; ++tj)
#pragma unroll
        for (int r = 0; r < 4; ++r) {
            float e = expf(acc[tj][r] - mx[r]);
            acc[tj][r] = e;
            sum[r] += e;
        }
#pragma unroll
    for (int off = 1; off < 16; off <<= 1)
#pragma unroll
        for (int r = 0; r < 4; ++r) sum[r] += __shfl_xor(sum[r], off);
    float inv[4];
#pragma unroll
    for (int r = 0; r < 4; ++r) inv[r] = 1.f / sum[r];
    float* base = out + (size_t)bh * L * L;
#pragma unroll
    for (int r = 0; r < 4; ++r) {
        int row = pass * 64 + wid * 16 + kg * 4 + r;
        if (row >= L) continue;
#pragma unroll
        for (int tj = 0; tj < 7; ++tj) {
            int col = tj * 16 + lrow;
            if (col < L) base[(size_t)row * L + col] = acc[tj][r] * inv[r];
        }
    }
}

// trend combine (Y fp32, row stride 192)
__global__ void trend_combine(const float* __restrict__ Y, const float* __restrict__ xmean,
                              float* __restrict__ dec_out)
{
    int idx = blockIdx.x * 256 + threadIdx.x;
    if (idx >= B * L * COUT) return;
    int o = idx % COUT; int l = (idx / COUT) % L; int b = idx / (COUT * L);
    int lm = (l + L - 1) % L, lp = (l + 1) % L;
    float v = xmean[(size_t)b * CIN + o]
            + Y[((size_t)b * L + lm) * 192 + o]
            + Y[((size_t)b * L + l ) * 192 + 64 + o]
            + Y[((size_t)b * L + lp) * 192 + 128 + o];
    dec_out[idx] = v;
}

// ---------------- MFMA forward DFT ----------------
__global__ __launch_bounds__(256) void dft_mfma(const unsigned short* __restrict__ X,
                                                const unsigned short* __restrict__ twf,
                                                float2* __restrict__ xf, int stride)
{
    int b = blockIdx.x / H, h = blockIdx.x % H;
    __shared__ unsigned short Xs[64][136];   // [e][t], t padded to 128
    int tid = threadIdx.x;
    for (int i = tid; i < L * E / 4; i += 256) {
        int t = i >> 4, e4 = (i & 15) * 4;
        ushort4 u = *(const ushort4*)&X[((size_t)b * L + t) * stride + h * E + e4];
        Xs[e4][t] = u.x; Xs[e4 + 1][t] = u.y; Xs[e4 + 2][t] = u.z; Xs[e4 + 3][t] = u.w;
    }
    for (int i = tid; i < 64 * 28; i += 256) {
        int e = i / 28, t = L + i % 28;
        Xs[e][t] = 0;
    }
    __syncthreads();
    int wid = tid >> 6, lane = tid & 63;
    int lrow = lane & 15, kg = lane >> 4;
    f32x4 acc[4] = {};
#pragma unroll
    for (int k0 = 0; k0 < 4; ++k0) {
        shortx8 bx = *(const shortx8*)&Xs[wid * 16 + lrow][k0 * 32 + kg * 8];
#pragma unroll
        for (int mi = 0; mi < 4; ++mi) {
            shortx8 aw = *(const shortx8*)&twf[(size_t)(mi * 16 + lrow) * 128 + k0 * 32 + kg * 8];
            acc[mi] = __builtin_amdgcn_mfma_f32_16x16x32_bf16(aw, bx, acc[mi], 0, 0, 0);
        }
    }
    int e = wid * 16 + lrow;
#pragma unroll
    for (int mi = 0; mi < 2; ++mi)
#pragma unroll
        for (int r = 0; r < 4; ++r) {
            int m = mi * 16 + kg * 4 + r;
            xf[((size_t)(h * MODES + m) * B + b) * E + e] = make_float2(acc[mi][r], acc[mi + 2][r]);
        }
}

// ---------------- MFMA iDFT ----------------
__global__ __launch_bounds__(256) void idft_mfma(const float2* __restrict__ sel,
                                                 const unsigned short* __restrict__ twi,
                                                 unsigned short* __restrict__ out, float scale)
{
    int b = blockIdx.x / H, h = blockIdx.x % H;
    __shared__ unsigned short Ss[64][72];    // [o][m'], m' = 32 re + 32 im
    int tid = threadIdx.x;
    for (int i = tid; i < MODES * E; i += 256) {
        int m = i >> 6, o = i & 63;
        float2 v = sel[((size_t)(h * MODES + m) * B + b) * E + o];
        Ss[o][m] = f2bf_n(v.x);
        Ss[o][m + 32] = f2bf_n(v.y);
    }
    __syncthreads();
    int wid = tid >> 6, lane = tid & 63;
    int lrow = lane & 15, kg = lane >> 4;
    f32x4 acc[2][4] = {};
#pragma unroll
    for (int k0 = 0; k0 < 2; ++k0) {
        shortx8 bs[4];
#pragma unroll
        for (int ni = 0; ni < 4; ++ni)
            bs[ni] = *(const shortx8*)&Ss[ni * 16 + lrow][k0 * 32 + kg * 8];
#pragma unroll
        for (int ti = 0; ti < 2; ++ti) {
            shortx8 at = *(const shortx8*)&twi[(size_t)((wid * 2 + ti) * 16 + lrow) * 64 + k0 * 32 + kg * 8];
#pragma unroll
            for (int ni = 0; ni < 4; ++ni)
                acc[ti][ni] = __builtin_amdgcn_mfma_f32_16x16x32_bf16(at, bs[ni], acc[ti][ni], 0, 0, 0);
        }
    }
#pragma unroll
    for (int ti = 0; ti < 2; ++ti)
#pragma unroll
        for (int ni = 0; ni < 4; ++ni)
#pragma unroll
            for (int r = 0; r < 4; ++r) {
                int t = (wid * 2 + ti) * 16 + kg * 4 + r;
                if (t < L) {
                    int o = ni * 16 + lrow;
                    out[((size_t)b * L + t) * D + h * E + o] = f2bf_n(acc[ti][ni][r] * scale);
                }
            }
}

// ---------------- per-(h,m) complex GEMM via MFMA, in place ----------------
// out[b][o] = sum_e X[b][e] * W[e][o]; W stored bf16 as Wt[hm][{re,im}][o][e]
__global__ __launch_bounds__(256) void mode_gemm_mfma(float2* __restrict__ xf,
                                                      const unsigned short* __restrict__ wt)
{
    int hm = blockIdx.x;
    int bt = blockIdx.y;
    __shared__ unsigned short XrS[32][72], XiS[32][72];
    __shared__ unsigned short WrS[64][72], WiS[64][72];
    int tid = threadIdx.x;
    // stage X (fp32 -> bf16)
    for (int i = tid; i < 32 * 64; i += 256) {
        int row = i >> 6, e = i & 63;
        float2 v = xf[((size_t)hm * B + bt * 32 + row) * E + e];
        XrS[row][e] = f2bf_n(v.x);
        XiS[row][e] = f2bf_n(v.y);
    }
    // stage W (already bf16, contiguous [o][e])
    const unsigned short* wr = wt + (size_t)hm * 2 * 4096;
    const unsigned short* wi = wr + 4096;
    for (int i = tid; i < 512; i += 256) {
        int o = i >> 3, e8 = (i & 7) * 8;
        *(shortx8*)&WrS[o][e8] = *(const shortx8*)&wr[(size_t)o * 64 + e8];
        *(shortx8*)&WiS[o][e8] = *(const shortx8*)&wi[(size_t)o * 64 + e8];
    }
    __syncthreads();
    int wid = tid >> 6, lane = tid & 63;
    int lrow = lane & 15, kg = lane >> 4;
    int n0 = wid * 16;
    f32x4 p1[2] = {}, p2[2] = {}, p3[2] = {}, p4[2] = {};
#pragma unroll
    for (int ks = 0; ks < 2; ++ks) {
        shortx8 bR = *(const shortx8*)&WrS[n0 + lrow][ks * 32 + kg * 8];
        shortx8 bI = *(const shortx8*)&WiS[n0 + lrow][ks * 32 + kg * 8];
#pragma unroll
        for (int m = 0; m < 2; ++m) {
            shortx8 aR = *(const shortx8*)&XrS[m * 16 + lrow][ks * 32 + kg * 8];
            shortx8 aI = *(const shortx8*)&XiS[m * 16 + lrow][ks * 32 + kg * 8];
            p1[m] = __builtin_amdgcn_mfma_f32_16x16x32_bf16(aR, bR, p1[m], 0, 0, 0);
            p2[m] = __builtin_amdgcn_mfma_f32_16x16x32_bf16(aI, bI, p2[m], 0, 0, 0);
            p3[m] = __builtin_amdgcn_mfma_f32_16x16x32_bf16(aR, bI, p3[m], 0, 0, 0);
            p4[m] = __builtin_amdgcn_mfma_f32_16x16x32_bf16(aI, bR, p4[m], 0, 0, 0);
        }
    }
    __syncthreads();
#pragma unroll
    for (int m = 0; m < 2; ++m)
#pragma unroll
        for (int r = 0; r < 4; ++r) {
            int row = m * 16 + kg * 4 + r;
            int o = n0 + lrow;
            xf[((size_t)hm * B + bt * 32 + row) * E + o] =
                make_float2(p1[m][r] - p2[m][r], p3[m][r] + p4[m][r]);
        }
}

// FourierCross steps 1-2 (fp32 freq domain)
__global__ __launch_bounds__(256) void fourier_qk(const float2* __restrict__ qf, float2* __restrict__ kf)
{
    int b = blockIdx.x / H, h = blockIdx.x % H;
    __shared__ float2 qm[MODES][E + 1], km[MODES][E + 1], vm[MODES][E + 1];
    __shared__ float tr[MODES][MODES + 1], ti[MODES][MODES + 1];
    for (int i = threadIdx.x; i < MODES * E; i += 256) {
        int m = i / E, e = i % E;
        size_t idx = ((size_t)(h * MODES + m) * B + b) * E + e;
        qm[m][e] = qf[idx];
        km[m][e] = kf[idx];
    }
    __syncthreads();
    for (int i = threadIdx.x; i < MODES * MODES; i += 256) {
        int x = i / MODES, y = i % MODES;
        float re = 0.f, im = 0.f;
        for (int e = 0; e < E; ++e) {
            float2 a = qm[x][e], k2 = km[y][e];
            re += a.x * k2.x - a.y * k2.y;
            im += a.x * k2.y + a.y * k2.x;
        }
        float aa = fminf(fmaxf(2.f * re, -30.f), 30.f);
        float b2 = 2.f * im;
        float den = coshf(aa) + cosf(b2);
        tr[x][y] = sinhf(aa) / den;
        ti[x][y] = sinf(b2) / den;
    }
    __syncthreads();
    for (int i = threadIdx.x; i < MODES * E; i += 256) {
        int x = i / E, e = i % E;
        float re = 0.f, im = 0.f;
        for (int y = 0; y < MODES; ++y) {
            float ar = tr[x][y], ai = ti[x][y];
            float2 kk = km[y][e];
            re += ar * kk.x - ai * kk.y;
            im += ar * kk.y + ai * kk.x;
        }
        vm[x][e] = make_float2(re, im);
    }
    __syncthreads();
    for (int i = threadIdx.x; i < MODES * E; i += 256) {
        int m = i / E, e = i % E;
        kf[((size_t)(h * MODES + m) * B + b) * E + e] = vm[m][e];
    }
}

// sigma + prior fused
__global__ __launch_bounds__(256) void sigma_prior(const unsigned short* __restrict__ enc,
                                                   const float* __restrict__ w,
                                                   const float* __restrict__ bias,
                                                   float* __restrict__ sig_out, float* __restrict__ prior)
{
    __shared__ float wsh[H][D];
    for (int i = threadIdx.x; i < H * D; i += 256) wsh[i / D][i % D] = w[i];
    __syncthreads();
    int wid = threadIdx.x / 64, lane = threadIdx.x % 64;
    int row = blockIdx.x * 4 + wid;
    const unsigned short* p = enc + (size_t)row * D;
    float xv[8];
#pragma unroll
    for (int i = 0; i < 8; ++i) xv[i] = bf2f(p[lane + i * 64]);
    int b = row / L, l = row % L;
#pragma unroll
    for (int h = 0; h < H; ++h) {
        float s = 0.f;
#pragma unroll
        for (int i = 0; i < 8; ++i) s += xv[i] * wsh[h][lane + i * 64];
        for (int off = 32; off; off >>= 1) s += __shfl_xor(s, off);
        float acc = s + bias[h];
        float sg = 1.f / (1.f + expf(-5.f * acc));
        float val = expf((sg + 1e-5f) * 1.0986122886681098f) - 1.f; // 3^u - 1
        if (lane == 0) sig_out[((size_t)b * H + h) * L + l] = val;
        float inv2 = 1.f / (2.f * val * val);
        float coef = INV_SQRT_2PI / val;
        float* pr = prior + (((size_t)b * H + h) * L + l) * L;
        for (int sc = lane; sc < L; sc += 64) {
            float d = (float)abs(l - sc);
            pr[sc] = expf(-d * d * inv2) * coef;
        }
    }
}

// series_decomp_multi via replicate-padded prefix sum
__global__ __launch_bounds__(256) void decomp_kernel(const unsigned short* __restrict__ in1,
                                                     const unsigned short* __restrict__ in2,
                                                     const float* __restrict__ w, const float* __restrict__ bc,
                                                     unsigned short* __restrict__ res, float* __restrict__ trend,
                                                     unsigned short* __restrict__ trend16, int tmode)
{
    int b = blockIdx.x / (D / 64);
    int d0 = (blockIdx.x % (D / 64)) * 64;
    __shared__ float P[125][65];
    __shared__ float qtot[4][64];
    int tid = threadIdx.x;
    int dd = tid & 63, q = tid >> 6;
    int p0 = q * 31;
    float run = 0.f;
#pragma unroll
    for (int i = 0; i < 31; ++i) {
        int p = p0 + i;
        int j = min(max(p - 12, 0), L - 1);
        size_t g = ((size_t)b * L + j) * D + d0 + dd;
        float v = bf2f(in1[g]);
        if (in2) v += bf2f(in2[g]);
        run += v;
        P[p + 1][dd] = run;
    }
    qtot[q][dd] = run;
    if (tid < 64) P[0][dd] = 0.f;
    __syncthreads();
    if (q > 0) {
        float off = qtot[0][dd];
        if (q > 1) off += qtot[1][dd];
        if (q > 2) off += qtot[2][dd];
#pragma unroll
        for (int i = 0; i < 31; ++i)
            P[p0 + i + 1][dd] += off;
    }
    __syncthreads();
    float w0 = w[0], w1 = w[1], b0 = bc[0], b1 = bc[1];
    for (int i = tid; i < L * 64; i += 256) {
        int l = i >> 6, d2 = i & 63;
        float s12 = P[l + 19][d2] - P[l + 7][d2];
        float s24 = P[l + 25][d2] - P[l + 1][d2];
        float x = P[l + 13][d2] - P[l + 12][d2];
        float m0 = s12 * (1.f / 12.f), m1 = s24 * (1.f / 24.f);
        float z0 = x * w0 + b0, z1 = x * w1 + b1;
        float zm = fmaxf(z0, z1);
        float e0 = expf(z0 - zm), e1 = expf(z1 - zm);
        float p0f = e0 / (e0 + e1);
        float mean = m0 * p0f + m1 * (1.f - p0f);
        size_t g = ((size_t)b * L + l) * D + d0 + d2;
        res[g] = f2bf_n(x - mean);
        if (tmode == 1) trend[g] = mean;
        else if (tmode == 2) {
            float tv = trend[g] + mean;
            trend[g] = tv;
            if (trend16) trend16[g] = f2bf_n(tv);
        }
    }
}

// fused my_layernorm: per-row LN then per-column mean subtract; one block per batch b.
__global__ __launch_bounds__(256) void ln_colsub(const unsigned short* __restrict__ x,
                                                 const float* __restrict__ g, const float* __restrict__ bb,
                                                 unsigned short* __restrict__ out)
{
    int b = blockIdx.x;
    __shared__ unsigned short xs[L][D];      // 100*512*2 = 102,400 B
    __shared__ float colmean[D];
    __shared__ float gs[D], bs2[D];
    int tid = threadIdx.x;
    for (int i = tid; i < L * D / 8; i += 256) {
        int l = i / 64, c8 = (i % 64) * 8;
        *(shortx8*)&xs[l][c8] = *(const shortx8*)&x[((size_t)b * L + l) * D + c8];
    }
    for (int i = tid; i < D; i += 256) { gs[i] = g[i]; bs2[i] = bb[i]; }
    __syncthreads();
    int wid = tid >> 6, lane = tid & 63;
    for (int l = wid; l < L; l += 4) {
        float v[8];
        float s = 0.f, s2 = 0.f;
#pragma unroll
        for (int i = 0; i < 8; ++i) {
            v[i] = bf2f(xs[l][lane + i * 64]);
            s += v[i]; s2 += v[i] * v[i];
        }
        for (int off = 32; off; off >>= 1) { s += __shfl_xor(s, off); s2 += __shfl_xor(s2, off); }
        float mu = s / (float)D;
        float var = s2 / (float)D - mu * mu;
        float rstd = rsqrtf(var + 1e-5f);
#pragma unroll
        for (int i = 0; i < 8; ++i) {
            int d = lane + i * 64;
            xs[l][d] = f2bf_n((v[i] - mu) * rstd * gs[d] + bs2[d]);
        }
    }
    __syncthreads();
    for (int c = tid; c < D; c += 256) {
        float s = 0.f;
        for (int l = 0; l < L; ++l) s += bf2f(xs[l][c]);
        colmean[c] = s * (1.f / (float)L);
    }
    __syncthreads();
    for (int i = tid; i < L * D; i += 256) {
        int l = i / D, c = i % D;
        out[((size_t)b * L + l) * D + c] = f2bf_n(bf2f(xs[l][c]) - colmean[c]);
    }
}

extern "C" void kernel_launch(void* const* d_in, const int* in_sizes, int n_in,
                              void* d_out, int out_size, void* d_ws, size_t ws_size,
                              hipStream_t stream)
{
    const float* x           = (const float*)d_in[0];
    const float* emb_enc_w   = (const float*)d_in[1];
    const float* emb_dec_w   = (const float*)d_in[2];
    const float* enc_proj_w  = (const float*)d_in[3];
    const float* enc_proj_b  = (const float*)d_in[4];
    const float* enc_sig_w   = (const float*)d_in[5];
    const float* enc_sig_b   = (const float*)d_in[6];
    const float* enc_four_wr = (const float*)d_in[7];
    const float* enc_four_wi = (const float*)d_in[8];
    const float* enc_ffn_w1  = (const float*)d_in[9];
    const float* enc_ffn_w2  = (const float*)d_in[10];
    const float* enc_dcmp_w  = (const float*)d_in[11];
    const float* enc_dcmp_b  = (const float*)d_in[12];
    const float* enc_norm_g  = (const float*)d_in[13];
    const float* enc_norm_b  = (const float*)d_in[14];
    const float* dec_proj_w  = (const float*)d_in[15];
    const float* dec_proj_b  = (const float*)d_in[16];
    const float* dec_four_wr = (const float*)d_in[17];
    const float* dec_four_wi = (const float*)d_in[18];
    const float* crs_proj_w  = (const float*)d_in[19];
    const float* crs_proj_b  = (const float*)d_in[20];
    const float* crs_four_wr = (const float*)d_in[21];
    const float* crs_four_wi = (const float*)d_in[22];
    const float* dec_ffn_w1  = (const float*)d_in[23];
    const float* dec_ffn_w2  = (const float*)d_in[24];
    const float* dec_dcmp_w  = (const float*)d_in[25];
    const float* dec_dcmp_b  = (const float*)d_in[26];
    const float* dec_trend_w = (const float*)d_in[27];
    const float* dec_norm_g  = (const float*)d_in[28];
    const float* dec_norm_b  = (const float*)d_in[29];
    const float* out_proj_w  = (const float*)d_in[30];
    const float* out_proj_b  = (const float*)d_in[31];

    float* ws = (float*)d_ws;
    size_t off = 0;
    float* pe    = ws + off; off += (size_t)L * D;
    float* xmean = ws + off; off += (size_t)B * CIN;
    float* bufF  = ws + off; off += BLD;           // fp32 scratch (trend Y)
    float* tacc  = ws + off; off += BLD;           // fp32 trend accumulator
    float2* xfc  = (float2*)(ws + off); off += 2 * BHEM;
    float2* kfc  = (float2*)(ws + off); off += 2 * BHEM;
    unsigned short* wtbf = (unsigned short*)(ws + off); off += (size_t)H * MODES * 2 * E * E / 2;
    // bf16 activation buffers
    unsigned short* qk16 = (unsigned short*)(ws + off); off += BLD;        // 2*BLD shorts (q|k fused, stride 1024)
    unsigned short* e16  = (unsigned short*)(ws + off); off += BLD / 2;
    unsigned short* c16  = (unsigned short*)(ws + off); off += BLD / 2;
    unsigned short* d16  = (unsigned short*)(ws + off); off += BLD / 2;
    unsigned short* h16  = (unsigned short*)(ws + off); off += BLD / 2;
    unsigned short* t16  = (unsigned short*)(ws + off); off += BLD / 2;
    unsigned short* im16 = (unsigned short*)(ws + off); off += (size_t)M_ROWS * KEMB / 2;
    // bf16 weights + twiddle tables
    unsigned short* wbf_encproj = (unsigned short*)(ws + off); off += (size_t)2 * 4 * D * D / 2;
    unsigned short* wbf_ffn1    = (unsigned short*)(ws + off); off += (size_t)2 * DFF * D / 2;
    unsigned short* wbf_ffn2    = (unsigned short*)(ws + off); off += (size_t)2 * D * DFF / 2;
    unsigned short* wbf_decproj = (unsigned short*)(ws + off); off += (size_t)4 * D * D / 2;
    unsigned short* wbf_crsproj = (unsigned short*)(ws + off); off += (size_t)4 * D * D / 2;
    unsigned short* wbf_dffn1   = (unsigned short*)(ws + off); off += (size_t)DFF * D / 2;
    unsigned short* wbf_dffn2   = (unsigned short*)(ws + off); off += (size_t)D * DFF / 2;
    unsigned short* wbf_embenc  = (unsigned short*)(ws + off); off += (size_t)D * KEMB / 2;
    unsigned short* wbf_embdec  = (unsigned short*)(ws + off); off += (size_t)D * KEMB / 2;
    unsigned short* wbf_trd     = (unsigned short*)(ws + off); off += (size_t)192 * D / 2;
    unsigned short* wbf_seas    = (unsigned short*)(ws + off); off += (size_t)64 * D / 2;
    unsigned short* twf         = (unsigned short*)(ws + off); off += (size_t)64 * 128 / 2;
    unsigned short* twi         = (unsigned short*)(ws + off); off += (size_t)128 * 64 / 2;
    unsigned short* a16 = qk16;               // decoder reuse of qk region
    unsigned short* b16 = qk16 + BLD;

    float* out       = (float*)d_out;
    float* dec_out   = out;
    float* series_out= out + (size_t)B * L * COUT;
    float* prior_out = series_out + 2 * BHLL;
    float* sigma_out = prior_out + 2 * BHLL;

    const int BH = B * H;

    init_consts<<<200, 256, 0, stream>>>(pe);
    init_tw<<<32, 256, 0, stream>>>(twf, twi);
    xmean_kernel<<<cdiv(B * CIN, 256), 256, 0, stream>>>(x, xmean);

    // merged weight prep (7 bulk bf16 conversions + 4 padded layouts) in ONE launch
    PrepArgs pa;
    pa.src[0] = enc_proj_w; pa.dst[0] = wbf_encproj; pa.n4[0] = 2 * 4 * D * D / 4;
    pa.src[1] = enc_ffn_w1; pa.dst[1] = wbf_ffn1;    pa.n4[1] = 2 * DFF * D / 4;
    pa.src[2] = enc_ffn_w2; pa.dst[2] = wbf_ffn2;    pa.n4[2] = 2 * D * DFF / 4;
    pa.src[3] = dec_proj_w; pa.dst[3] = wbf_decproj; pa.n4[3] = 4 * D * D / 4;
    pa.src[4] = crs_proj_w; pa.dst[4] = wbf_crsproj; pa.n4[4] = 4 * D * D / 4;
    pa.src[5] = dec_ffn_w1; pa.dst[5] = wbf_dffn1;   pa.n4[5] = DFF * D / 4;
    pa.src[6] = dec_ffn_w2; pa.dst[6] = wbf_dffn2;   pa.n4[6] = D * DFF / 4;
    pa.emb_enc = emb_enc_w; pa.emb_dec = emb_dec_w; pa.trend_w = dec_trend_w; pa.seas_w = out_proj_w;
    pa.d_embenc = wbf_embenc; pa.d_embdec = wbf_embdec; pa.d_trd = wbf_trd; pa.d_seas = wbf_seas;
    int total4 = 0;
    for (int s = 0; s < 7; ++s) total4 += pa.n4[s];
    int padTotal = 2 * D * KEMB + 192 * D + 64 * D;
    prep_all<<<2048, 256, 0, stream>>>(pa, total4, padTotal);
    transpose_wb<<<H * E, 256, 0, stream>>>(enc_four_wr, enc_four_wi, wtbf);

    auto gemm = [&](const unsigned short* A, const unsigned short* Wb, const float* bias, const float* pe_,
                    float* C, unsigned short* Cb, int N, int Nout, int K, int act, int accum) {
        if (N % 128 == 0) {
            dim3 grid(N / 128, M_ROWS / 128);
            gemm_mfma<128><<<grid, 256, 0, stream>>>(A, Wb, bias, pe_, C, Cb, Nout, K, act, accum);
        } else {
            dim3 grid(N / 64, M_ROWS / 128);
            gemm_mfma<64><<<grid, 256, 0, stream>>>(A, Wb, bias, pe_, C, Cb, Nout, K, act, accum);
        }
    };
    dim3 mg_grid(H * MODES, B / 32);
    dim3 sc_grid(BH, 2);

    // encoder embedding
    im2col_emb<<<cdiv(M_ROWS * KEMB, 256), 256, 0, stream>>>(x, nullptr, im16);
    gemm(im16, wbf_embenc, nullptr, pe, nullptr, e16, D, D, KEMB, 0, 0);

    for (int i = 0; i < 2; ++i) {
        const unsigned short* Wp = wbf_encproj + (size_t)i * 4 * D * D;
        const float* bp = enc_proj_b + (size_t)i * 4 * D;
        float* series_i = series_out + (size_t)i * BHLL;
        float* prior_i  = prior_out  + (size_t)i * BHLL;
        float* sigma_i  = sigma_out  + (size_t)i * B * H * L;

        gemm(e16, Wp, bp, nullptr, nullptr, qk16, 1024, 1024, D, 0, 0);       // fused q+k
        dft_mfma<<<BH, 256, 0, stream>>>(qk16, twf, xfc, 1024);
        mode_gemm_mfma<<<mg_grid, 256, 0, stream>>>(xfc, wtbf);
        idft_mfma<<<BH, 256, 0, stream>>>(xfc, twi, c16, 1.f / (float)L);
        gemm(c16, Wp + (size_t)3 * D * D, bp + 3 * D, nullptr, nullptr, d16, D, D, D, 0, 0); // attn_out
        scores_softmax<<<sc_grid, 256, 0, stream>>>(qk16, series_i);
        sigma_prior<<<M_ROWS / 4, 256, 0, stream>>>(e16, enc_sig_w + (size_t)i * H * D,
                                                    enc_sig_b + (size_t)i * H, sigma_i, prior_i);
        decomp_kernel<<<B * (D / 64), 256, 0, stream>>>(e16, d16, enc_dcmp_w + (size_t)(i * 2 + 0) * NK,
                                                        enc_dcmp_b + (size_t)(i * 2 + 0) * NK, h16, nullptr, nullptr, 0);
        gemm(h16, wbf_ffn1 + (size_t)i * DFF * D, nullptr, nullptr, nullptr, c16, DFF, DFF, D, 1, 0);
        gemm(c16, wbf_ffn2 + (size_t)i * D * DFF, nullptr, nullptr, nullptr, d16, D, D, DFF, 0, 0);
        decomp_kernel<<<B * (D / 64), 256, 0, stream>>>(h16, d16, enc_dcmp_w + (size_t)(i * 2 + 1) * NK,
                                                        enc_dcmp_b + (size_t)(i * 2 + 1) * NK, e16, nullptr, nullptr, 0);
    }
    // encoder final my_layernorm (fused LN + column-mean subtract), in place on e16
    ln_colsub<<<B, 256, 0, stream>>>(e16, enc_norm_g, enc_norm_b, e16);

    // ---------------- decoder ----------------
    transpose_wb<<<H * E, 256, 0, stream>>>(dec_four_wr, dec_four_wi, wtbf);
    im2col_emb<<<cdiv(M_ROWS * KEMB, 256), 256, 0, stream>>>(x, xmean, im16);
    gemm(im16, wbf_embdec, nullptr, pe, nullptr, a16, D, D, KEMB, 0, 0);           // dec
    gemm(a16, wbf_decproj, dec_proj_b, nullptr, nullptr, b16, D, D, D, 0, 0);      // q
    dft_mfma<<<BH, 256, 0, stream>>>(b16, twf, xfc, D);
    mode_gemm_mfma<<<mg_grid, 256, 0, stream>>>(xfc, wtbf);
    idft_mfma<<<BH, 256, 0, stream>>>(xfc, twi, c16, 1.f / (float)L);
    gemm(c16, wbf_decproj + (size_t)3 * D * D, dec_proj_b + 3 * D, nullptr, nullptr, d16, D, D, D, 0, 0); // sa
    decomp_kernel<<<B * (D / 64), 256, 0, stream>>>(a16, d16, dec_dcmp_w, dec_dcmp_b, h16, tacc, nullptr, 1); // h, t1

    gemm(h16, wbf_crsproj, crs_proj_b, nullptr, nullptr, b16, D, D, D, 0, 0);      // qc
    dft_mfma<<<BH, 256, 0, stream>>>(b16, twf, xfc, D);                            // qf
    gemm(e16, wbf_crsproj + (size_t)D * D, crs_proj_b + D, nullptr, nullptr, b16, D, D, D, 0, 0); // kc
    dft_mfma<<<BH, 256, 0, stream>>>(b16, twf, kfc, D);                            // kf
    transpose_wb<<<H * E, 256, 0, stream>>>(crs_four_wr, crs_four_wi, wtbf);
    fourier_qk<<<BH, 256, 0, stream>>>(xfc, kfc);                                  // kfc := qkv
    mode_gemm_mfma<<<mg_grid, 256, 0, stream>>>(kfc, wtbf);
    idft_mfma<<<BH, 256, 0, stream>>>(kfc, twi, c16, 1.f / ((float)L * (float)D * (float)D));
    gemm(c16, wbf_crsproj + (size_t)3 * D * D, crs_proj_b + 3 * D, nullptr, nullptr, d16, D, D, D, 0, 0); // ca
    decomp_kernel<<<B * (D / 64), 256, 0, stream>>>(h16, d16, dec_dcmp_w + NK, dec_dcmp_b + NK, a16, tacc, nullptr, 2); // h2, t2

    gemm(a16, wbf_dffn1, nullptr, nullptr, nullptr, c16, DFF, DFF, D, 1, 0);
    gemm(c16, wbf_dffn2, nullptr, nullptr, nullptr, d16, D, D, DFF, 0, 0);
    decomp_kernel<<<B * (D / 64), 256, 0, stream>>>(a16, d16, dec_dcmp_w + 2 * NK, dec_dcmp_b + 2 * NK, b16, tacc, t16, 2); // h3, t3 (+bf16 trend)

    // trend conv: stacked-tap GEMM (K=512, N=192, fp32 out) -> combine with trend_init (xmean)
    gemm(t16, wbf_trd, nullptr, nullptr, bufF, nullptr, 192, 192, D, 0, 0);
    trend_combine<<<cdiv(B * L * COUT, 256), 256, 0, stream>>>(bufF, xmean, dec_out);

    // final layernorm (fused) + seasonal projection accumulated into dec_out
    ln_colsub<<<B, 256, 0, stream>>>(b16, dec_norm_g, dec_norm_b, d16);
    gemm(d16, wbf_seas, out_proj_b, nullptr, dec_out, nullptr, 64, COUT, D, 0, 1);
}

// Round 16
// 1144.868 us; speedup vs baseline: 1.1681x; 1.0350x over previous
//
#include <hip/hip_runtime.h>
#include <hip/hip_bf16.h>
#include <cmath>

constexpr int B = 128, L = 100, CIN = 55, COUT = 55;
constexpr int D = 512, H = 8, DFF = 512, MODES = 32, E = 64;
constexpr int NK = 2;
constexpr int M_ROWS = B * L; // 12800
constexpr int KEMB = 192;     // 55*3=165 padded to 32*6
constexpr size_t BLD  = (size_t)B * L * D;         // 6,553,600
constexpr size_t BHEM = (size_t)B * H * E * MODES; // 2,097,152 complex elems
constexpr size_t BHLL = (size_t)B * H * L * L;     // 10,240,000
constexpr float INV_SQRT_2PI = 0.3989422804014327f;

static inline int cdiv(int a, int b) { return (a + b - 1) / b; }

typedef short shortx8 __attribute__((ext_vector_type(8)));
typedef float f32x4 __attribute__((ext_vector_type(4)));

__device__ inline unsigned short f2bf(float f)    // RNE (weight prep)
{
    unsigned int u = __float_as_uint(f);
    unsigned int r = (u + 0x7FFFu + ((u >> 16) & 1u)) >> 16;
    return (unsigned short)r;
}
__device__ inline unsigned short f2bf_n(float f)  // native cvt
{
    union { __hip_bfloat16 h; unsigned short u; } cv;
    cv.h = __float2bfloat16(f);
    return cv.u;
}
__device__ inline float bf2f(unsigned short u)
{
    union { unsigned int i; float f; } c;
    c.i = (unsigned int)u << 16;
    return c.f;
}

// ---------------- constants ----------------
__global__ void init_consts(float* __restrict__ pe)
{
    int idx = blockIdx.x * 256 + threadIdx.x;
    if (idx < L * D) {
        int l = idx / D, d = idx % D;
        int i2 = d & ~1;
        float div = expf((float)i2 * (-logf(10000.f) / (float)D));
        float ang = (float)l * div;
        pe[idx] = (d & 1) ? cosf(ang) : sinf(ang);
    }
}

// bf16 twiddle tables for MFMA DFT/iDFT
__global__ void init_tw(unsigned short* __restrict__ twf, unsigned short* __restrict__ twi)
{
    int idx = blockIdx.x * 256 + threadIdx.x;
    if (idx >= 64 * 128) return;
    {
        int mp = idx / 128, t = idx % 128;
        float v = 0.f;
        if (t < L) {
            if (mp < 32) v = cosf(2.f * 3.14159265358979323846f * (float)mp * (float)t / (float)L);
            else v = -sinf(2.f * 3.14159265358979323846f * (float)(mp - 32) * (float)t / (float)L);
        }
        twf[idx] = f2bf(v);
    }
    {
        int t = idx / 64, mp = idx % 64;
        float v = 0.f;
        if (t < L) {
            if (mp == 0) v = 1.f;
            else if (mp < 32) v = 2.f * cosf(2.f * 3.14159265358979323846f * (float)mp * (float)t / (float)L);
            else if (mp == 32) v = 0.f;
            else v = -2.f * sinf(2.f * 3.14159265358979323846f * (float)(mp - 32) * (float)t / (float)L);
        }
        twi[idx] = f2bf(v);
    }
}

__global__ void xmean_kernel(const float* __restrict__ x, float* __restrict__ xm)
{
    int idx = blockIdx.x * 256 + threadIdx.x;
    if (idx >= B * CIN) return;
    int b = idx / CIN, c = idx % CIN;
    float s = 0.f;
    for (int l = 0; l < L; ++l) s += x[((size_t)b * L + l) * CIN + c];
    xm[idx] = s * (1.f / (float)L);
}

// ---------------- single merged weight-prep kernel ----------------
struct PrepArgs {
    const float* src[7];
    unsigned short* dst[7];
    int n4[7];               // float4 count per segment
    const float* emb_enc; const float* emb_dec; const float* trend_w; const float* seas_w;
    unsigned short* d_embenc; unsigned short* d_embdec; unsigned short* d_trd; unsigned short* d_seas;
};
__global__ __launch_bounds__(256) void prep_all(PrepArgs a, int total4, int padTotal)
{
    for (int i = blockIdx.x * 256 + threadIdx.x; i < total4 + padTotal; i += gridDim.x * 256) {
        if (i < total4) {
            int idx = i, s = 0;
            while (idx >= a.n4[s]) { idx -= a.n4[s]; ++s; }
            float4 v = *(const float4*)&a.src[s][(size_t)idx * 4];
            ushort4 h;
            h.x = f2bf(v.x); h.y = f2bf(v.y); h.z = f2bf(v.z); h.w = f2bf(v.w);
            *(ushort4*)&a.dst[s][(size_t)idx * 4] = h;
            continue;
        }
        int p = i - total4;
        if (p < D * KEMB) {
            int r = p / KEMB, k = p % KEMB;
            a.d_embenc[p] = (k < CIN * 3) ? f2bf(a.emb_enc[(size_t)r * (CIN * 3) + k]) : (unsigned short)0;
        } else if ((p -= D * KEMB) < D * KEMB) {
            int r = p / KEMB, k = p % KEMB;
            a.d_embdec[p] = (k < CIN * 3) ? f2bf(a.emb_dec[(size_t)r * (CIN * 3) + k]) : (unsigned short)0;
        } else if ((p -= D * KEMB) < 192 * D) {
            int n = p / D, d = p % D;
            int j = n / 64, o = n % 64;
            a.d_trd[p] = (o < COUT) ? f2bf(a.trend_w[(size_t)o * (D * 3) + d * 3 + j]) : (unsigned short)0;
        } else {
            p -= 192 * D;
            int r = p / D, k = p % D;
            a.d_seas[p] = (r < COUT) ? f2bf(a.seas_w[(size_t)r * D + k]) : (unsigned short)0;
        }
    }
}

// Fourier weight transpose -> bf16 [hm][{re,im}][o][e]; one block per (h,o)
__global__ __launch_bounds__(256) void transpose_wb(const float* __restrict__ wr, const float* __restrict__ wi,
                                                    unsigned short* __restrict__ wt)
{
    int h = blockIdx.x / E, o = blockIdx.x % E;
    __shared__ float tr[64][33], ti[64][33];
    for (int i = threadIdx.x; i < E * MODES; i += 256) {
        int e = i >> 5, m = i & 31;
        size_t s = (((size_t)h * E + e) * E + o) * MODES + m;
        tr[e][m] = wr[s]; ti[e][m] = wi[s];
    }
    __syncthreads();
    for (int i = threadIdx.x; i < MODES * E; i += 256) {
        int m = i >> 6, e = i & 63;
        size_t base = ((size_t)(h * MODES + m) * 2) * 4096 + (size_t)o * 64 + e;
        wt[base] = f2bf(tr[e][m]);
        wt[base + 4096] = f2bf(ti[e][m]);
    }
}

// im2col for kernel-3 circular conv: bf16 out
__global__ void im2col_emb(const float* __restrict__ x, const float* __restrict__ xmean,
                           unsigned short* __restrict__ A2)
{
    int idx = blockIdx.x * 256 + threadIdx.x;
    if (idx >= M_ROWS * KEMB) return;
    int k = idx % KEMB, m = idx / KEMB;
    float v = 0.f;
    if (k < CIN * 3) {
        int c = k / 3, j = k % 3;
        int l = m % L, b = m / L;
        int ls = l + j - 1; ls = (ls + L) % L;
        v = x[((size_t)b * L + ls) * CIN + c];
        if (xmean) v -= xmean[(size_t)b * CIN + c];
    }
    A2[idx] = f2bf(v);
}

// ---------------- bf16 MFMA GEMM, double-buffered LDS, ONE barrier per K-step ----------------
template<int BN>
__global__ __launch_bounds__(256) void gemm_mfma(const unsigned short* __restrict__ A,
                                                 const unsigned short* __restrict__ Wb,
                                                 const float* __restrict__ bias, const float* __restrict__ pe,
                                                 float* __restrict__ C, unsigned short* __restrict__ Cb,
                                                 int Nout, int K, int act, int accum)
{
    constexpr int NI = BN / 32;
    constexpr int BI = BN / 64;
    __shared__ unsigned short As[2][128][40];
    __shared__ unsigned short Bs[2][BN][40];
    int tid = threadIdx.x;
    int row0 = blockIdx.y * 128, col0 = blockIdx.x * BN;
    int wid = tid >> 6, lane = tid & 63;
    int wm = wid >> 1, wn = wid & 1;
    int lrow = lane & 15, kg = lane >> 4;
    int ar = tid >> 2, ac8 = (tid & 3) * 8;
    f32x4 acc[4][NI] = {};
    shortx8 rah[2], rbh[BI];

    auto loadG = [&](int k0) {
#pragma unroll
        for (int p = 0; p < 2; ++p)
            rah[p] = *(const shortx8*)&A[(size_t)(row0 + p * 64 + ar) * K + k0 + ac8];
#pragma unroll
        for (int p = 0; p < BI; ++p)
            rbh[p] = *(const shortx8*)&Wb[(size_t)(col0 + p * 64 + ar) * K + k0 + ac8];
    };
    auto storeLDS = [&](int buf) {
#pragma unroll
        for (int p = 0; p < 2; ++p)
            *(shortx8*)&As[buf][p * 64 + ar][ac8] = rah[p];
#pragma unroll
        for (int p = 0; p < BI; ++p)
            *(shortx8*)&Bs[buf][p * 64 + ar][ac8] = rbh[p];
    };

    int nk = K >> 5;
    loadG(0);
    storeLDS(0);
    if (nk > 1) loadG(32);
    __syncthreads();
    int cur = 0;
    for (int s = 0; s < nk; ++s) {
        if (s + 1 < nk) {
            storeLDS(cur ^ 1);                 // tile s+1 (regs) -> other buffer
            if (s + 2 < nk) loadG((s + 2) << 5); // issue loads for tile s+2
        }
        shortx8 av[4], bv[NI];
#pragma unroll
        for (int mi = 0; mi < 4; ++mi)
            av[mi] = *(const shortx8*)&As[cur][wm * 64 + mi * 16 + lrow][kg * 8];
#pragma unroll
        for (int ni = 0; ni < NI; ++ni)
            bv[ni] = *(const shortx8*)&Bs[cur][wn * (BN / 2) + ni * 16 + lrow][kg * 8];
#pragma unroll
        for (int mi = 0; mi < 4; ++mi)
#pragma unroll
            for (int ni = 0; ni < NI; ++ni)
                acc[mi][ni] = __builtin_amdgcn_mfma_f32_16x16x32_bf16(av[mi], bv[ni], acc[mi][ni], 0, 0, 0);
        if (s + 1 < nk) __syncthreads();
        cur ^= 1;
    }
#pragma unroll
    for (int mi = 0; mi < 4; ++mi) {
#pragma unroll
        for (int ni = 0; ni < NI; ++ni) {
            int col = col0 + wn * (BN / 2) + ni * 16 + lrow;
            if (col >= Nout) continue;
#pragma unroll
            for (int r = 0; r < 4; ++r) {
                int row = row0 + wm * 64 + mi * 16 + kg * 4 + r;
                float v = acc[mi][ni][r];
                if (bias) v += bias[col];
                if (pe) v += pe[(size_t)(row % L) * Nout + col];
                if (act) v = 0.5f * v * (1.f + erff(v * 0.70710678118654752f));
                size_t o = (size_t)row * Nout + col;
                if (Cb) Cb[o] = f2bf_n(v);
                else if (accum) C[o] += v;
                else C[o] = v;
            }
        }
    }
}

// ---------------- fused QK^T/8 + row-softmax (bf16 input, row stride 1024) ----------------
__global__ __launch_bounds__(256) void scores_softmax(const unsigned short* __restrict__ QK,
                                                      float* __restrict__ out)
{
    int bh = blockIdx.x, b = bh / H, h = bh % H;
    int pass = blockIdx.y;
    __shared__ unsigned short Ks[112][72];
    __shared__ unsigned short Qs[64][72];
    int tid = threadIdx.x;
    int srow = tid >> 4, sc4 = (tid & 15) * 4;
#pragma unroll
    for (int i = 0; i < 7; ++i) {
        int r = i * 16 + srow;
        ushort4 hh = {0, 0, 0, 0};
        if (r < L) hh = *(const ushort4*)&QK[((size_t)b * L + r) * 1024 + 512 + h * E + sc4];
        *(ushort4*)&Ks[r][sc4] = hh;
    }
#pragma unroll
    for (int i = 0; i < 4; ++i) {
        int r = i * 16 + srow;
        int gr = pass * 64 + r;
        ushort4 hh = {0, 0, 0, 0};
        if (gr < L) hh = *(const ushort4*)&QK[((size_t)b * L + gr) * 1024 + h * E + sc4];
        *(ushort4*)&Qs[r][sc4] = hh;
    }
    __syncthreads();
    int wid = tid >> 6, lane = tid & 63;
    int lrow = lane & 15, kg = lane >> 4;
    f32x4 acc[7] = {};
#pragma unroll
    for (int ks = 0; ks < 2; ++ks) {
        shortx8 aq = *(const shortx8*)&Qs[wid * 16 + lrow][ks * 32 + kg * 8];
#pragma unroll
        for (int tj = 0; tj < 7; ++tj) {
            shortx8 bk = *(const shortx8*)&Ks[tj * 16 + lrow][ks * 32 + kg * 8];
            acc[tj] = __builtin_amdgcn_mfma_f32_16x16x32_bf16(aq, bk, acc[tj], 0, 0, 0);
        }
    }
    float mx[4] = {-1e30f, -1e30f, -1e30f, -1e30f};
#pragma unroll
    for (int tj = 0; tj < 7; ++tj) {
        bool valid = (tj * 16 + lrow) < L;
#pragma unroll
        for (int r = 0; r < 4; ++r) {
            float v = acc[tj][r] * 0.125f;
            acc[tj][r] = valid ? v : -1e30f;
            if (valid) mx[r] = fmaxf(mx[r], v);
        }
    }
#pragma unroll
    for (int off = 1; off < 16; off <<= 1)
#pragma unroll
        for (int r = 0; r < 4; ++r) mx[r] = fmaxf(mx[r], __shfl_xor(mx[r], off));
    float sum[4] = {0.f, 0.f, 0.f, 0.f};
#pragma unroll
    for (int tj = 0; tj < 7; ++tj)
#pragma unroll
        for (int r = 0; r < 4; ++r) {
            float e = expf(acc[tj][r] - mx[r]);
            acc[tj][r] = e;
            sum[r] += e;
        }
#pragma unroll
    for (int off = 1; off < 16; off <<= 1)
#pragma unroll
        for (int r = 0; r < 4; ++r) sum[r] += __shfl_xor(sum[r], off);
    float inv[4];
#pragma unroll
    for (int r = 0; r < 4; ++r) inv[r] = 1.f / sum[r];
    float* base = out + (size_t)bh * L * L;
#pragma unroll
    for (int r = 0; r < 4; ++r) {
        int row = pass * 64 + wid * 16 + kg * 4 + r;
        if (row >= L) continue;
#pragma unroll
        for (int tj = 0; tj < 7; ++tj) {
            int col = tj * 16 + lrow;
            if (col < L) base[(size_t)row * L + col] = acc[tj][r] * inv[r];
        }
    }
}

// trend combine (Y fp32, row stride 192)
__global__ void trend_combine(const float* __restrict__ Y, const float* __restrict__ xmean,
                              float* __restrict__ dec_out)
{
    int idx = blockIdx.x * 256 + threadIdx.x;
    if (idx >= B * L * COUT) return;
    int o = idx % COUT; int l = (idx / COUT) % L; int b = idx / (COUT * L);
    int lm = (l + L - 1) % L, lp = (l + 1) % L;
    float v = xmean[(size_t)b * CIN + o]
            + Y[((size_t)b * L + lm) * 192 + o]
            + Y[((size_t)b * L + l ) * 192 + 64 + o]
            + Y[((size_t)b * L + lp) * 192 + 128 + o];
    dec_out[idx] = v;
}

// ---------------- MFMA forward DFT ----------------
__global__ __launch_bounds__(256) void dft_mfma(const unsigned short* __restrict__ X,
                                                const unsigned short* __restrict__ twf,
                                                float2* __restrict__ xf, int stride)
{
    int b = blockIdx.x / H, h = blockIdx.x % H;
    __shared__ unsigned short Xs[64][136];   // [e][t], t padded to 128
    int tid = threadIdx.x;
    for (int i = tid; i < L * E / 4; i += 256) {
        int t = i >> 4, e4 = (i & 15) * 4;
        ushort4 u = *(const ushort4*)&X[((size_t)b * L + t) * stride + h * E + e4];
        Xs[e4][t] = u.x; Xs[e4 + 1][t] = u.y; Xs[e4 + 2][t] = u.z; Xs[e4 + 3][t] = u.w;
    }
    for (int i = tid; i < 64 * 28; i += 256) {
        int e = i / 28, t = L + i % 28;
        Xs[e][t] = 0;
    }
    __syncthreads();
    int wid = tid >> 6, lane = tid & 63;
    int lrow = lane & 15, kg = lane >> 4;
    f32x4 acc[4] = {};
#pragma unroll
    for (int k0 = 0; k0 < 4; ++k0) {
        shortx8 bx = *(const shortx8*)&Xs[wid * 16 + lrow][k0 * 32 + kg * 8];
#pragma unroll
        for (int mi = 0; mi < 4; ++mi) {
            shortx8 aw = *(const shortx8*)&twf[(size_t)(mi * 16 + lrow) * 128 + k0 * 32 + kg * 8];
            acc[mi] = __builtin_amdgcn_mfma_f32_16x16x32_bf16(aw, bx, acc[mi], 0, 0, 0);
        }
    }
    int e = wid * 16 + lrow;
#pragma unroll
    for (int mi = 0; mi < 2; ++mi)
#pragma unroll
        for (int r = 0; r < 4; ++r) {
            int m = mi * 16 + kg * 4 + r;
            xf[((size_t)(h * MODES + m) * B + b) * E + e] = make_float2(acc[mi][r], acc[mi + 2][r]);
        }
}

// ---------------- MFMA iDFT ----------------
__global__ __launch_bounds__(256) void idft_mfma(const float2* __restrict__ sel,
                                                 const unsigned short* __restrict__ twi,
                                                 unsigned short* __restrict__ out, float scale)
{
    int b = blockIdx.x / H, h = blockIdx.x % H;
    __shared__ unsigned short Ss[64][72];    // [o][m'], m' = 32 re + 32 im
    int tid = threadIdx.x;
    for (int i = tid; i < MODES * E; i += 256) {
        int m = i >> 6, o = i & 63;
        float2 v = sel[((size_t)(h * MODES + m) * B + b) * E + o];
        Ss[o][m] = f2bf_n(v.x);
        Ss[o][m + 32] = f2bf_n(v.y);
    }
    __syncthreads();
    int wid = tid >> 6, lane = tid & 63;
    int lrow = lane & 15, kg = lane >> 4;
    f32x4 acc[2][4] = {};
#pragma unroll
    for (int k0 = 0; k0 < 2; ++k0) {
        shortx8 bs[4];
#pragma unroll
        for (int ni = 0; ni < 4; ++ni)
            bs[ni] = *(const shortx8*)&Ss[ni * 16 + lrow][k0 * 32 + kg * 8];
#pragma unroll
        for (int ti = 0; ti < 2; ++ti) {
            shortx8 at = *(const shortx8*)&twi[(size_t)((wid * 2 + ti) * 16 + lrow) * 64 + k0 * 32 + kg * 8];
#pragma unroll
            for (int ni = 0; ni < 4; ++ni)
                acc[ti][ni] = __builtin_amdgcn_mfma_f32_16x16x32_bf16(at, bs[ni], acc[ti][ni], 0, 0, 0);
        }
    }
#pragma unroll
    for (int ti = 0; ti < 2; ++ti)
#pragma unroll
        for (int ni = 0; ni < 4; ++ni)
#pragma unroll
            for (int r = 0; r < 4; ++r) {
                int t = (wid * 2 + ti) * 16 + kg * 4 + r;
                if (t < L) {
                    int o = ni * 16 + lrow;
                    out[((size_t)b * L + t) * D + h * E + o] = f2bf_n(acc[ti][ni][r] * scale);
                }
            }
}

// ---------------- per-(h,m) complex GEMM via MFMA, in place ----------------
// out[b][o] = sum_e X[b][e] * W[e][o]; W stored bf16 as Wt[hm][{re,im}][o][e]
__global__ __launch_bounds__(256) void mode_gemm_mfma(float2* __restrict__ xf,
                                                      const unsigned short* __restrict__ wt)
{
    int hm = blockIdx.x;
    int bt = blockIdx.y;
    __shared__ unsigned short XrS[32][72], XiS[32][72];
    __shared__ unsigned short WrS[64][72], WiS[64][72];
    int tid = threadIdx.x;
    // stage X (fp32 -> bf16)
    for (int i = tid; i < 32 * 64; i += 256) {
        int row = i >> 6, e = i & 63;
        float2 v = xf[((size_t)hm * B + bt * 32 + row) * E + e];
        XrS[row][e] = f2bf_n(v.x);
        XiS[row][e] = f2bf_n(v.y);
    }
    // stage W (already bf16, contiguous [o][e])
    const unsigned short* wr = wt + (size_t)hm * 2 * 4096;
    const unsigned short* wi = wr + 4096;
    for (int i = tid; i < 512; i += 256) {
        int o = i >> 3, e8 = (i & 7) * 8;
        *(shortx8*)&WrS[o][e8] = *(const shortx8*)&wr[(size_t)o * 64 + e8];
        *(shortx8*)&WiS[o][e8] = *(const shortx8*)&wi[(size_t)o * 64 + e8];
    }
    __syncthreads();
    int wid = tid >> 6, lane = tid & 63;
    int lrow = lane & 15, kg = lane >> 4;
    int n0 = wid * 16;
    f32x4 p1[2] = {}, p2[2] = {}, p3[2] = {}, p4[2] = {};
#pragma unroll
    for (int ks = 0; ks < 2; ++ks) {
        shortx8 bR = *(const shortx8*)&WrS[n0 + lrow][ks * 32 + kg * 8];
        shortx8 bI = *(const shortx8*)&WiS[n0 + lrow][ks * 32 + kg * 8];
#pragma unroll
        for (int m = 0; m < 2; ++m) {
            shortx8 aR = *(const shortx8*)&XrS[m * 16 + lrow][ks * 32 + kg * 8];
            shortx8 aI = *(const shortx8*)&XiS[m * 16 + lrow][ks * 32 + kg * 8];
            p1[m] = __builtin_amdgcn_mfma_f32_16x16x32_bf16(aR, bR, p1[m], 0, 0, 0);
            p2[m] = __builtin_amdgcn_mfma_f32_16x16x32_bf16(aI, bI, p2[m], 0, 0, 0);
            p3[m] = __builtin_amdgcn_mfma_f32_16x16x32_bf16(aR, bI, p3[m], 0, 0, 0);
            p4[m] = __builtin_amdgcn_mfma_f32_16x16x32_bf16(aI, bR, p4[m], 0, 0, 0);
        }
    }
    __syncthreads();
#pragma unroll
    for (int m = 0; m < 2; ++m)
#pragma unroll
        for (int r = 0; r < 4; ++r) {
            int row = m * 16 + kg * 4 + r;
            int o = n0 + lrow;
            xf[((size_t)hm * B + bt * 32 + row) * E + o] =
                make_float2(p1[m][r] - p2[m][r], p3[m][r] + p4[m][r]);
        }
}

// ---------------- FourierCross steps 1-2 via MFMA ----------------
// per (b,h): qk[x][y] = ctanh(sum_e q[x][e]k[y][e]); qkv[x][e] = sum_y qk[x][y]k[y][e]; writes over kf
__global__ __launch_bounds__(256) void fourier_qk_mfma(const float2* __restrict__ qf, float2* __restrict__ kf)
{
    int b = blockIdx.x / H, h = blockIdx.x % H;
    __shared__ unsigned short QR[32][72], QI[32][72], KR[32][72], KI[32][72];
    __shared__ unsigned short KTR[64][40], KTI[64][40];
    __shared__ unsigned short TR[32][40], TI[32][40];
    int tid = threadIdx.x;
    for (int i = tid; i < MODES * E; i += 256) {
        int m = i >> 6, e = i & 63;
        size_t idx = ((size_t)(h * MODES + m) * B + b) * E + e;
        float2 q = qf[idx], k = kf[idx];
        unsigned short kr = f2bf_n(k.x), ki = f2bf_n(k.y);
        QR[m][e] = f2bf_n(q.x); QI[m][e] = f2bf_n(q.y);
        KR[m][e] = kr; KI[m][e] = ki;
        KTR[e][m] = kr; KTI[e][m] = ki;
    }
    __syncthreads();
    int wid = tid >> 6, lane = tid & 63;
    int lrow = lane & 15, kg = lane >> 4;
    // step 1: M=32(x) x N=32(y) x K=64(e); wave tile (xt, yt)
    {
        int xt = wid >> 1, yt = wid & 1;
        f32x4 p1 = {}, p2 = {}, p3 = {}, p4 = {};
#pragma unroll
        for (int ks = 0; ks < 2; ++ks) {
            shortx8 aR = *(const shortx8*)&QR[xt * 16 + lrow][ks * 32 + kg * 8];
            shortx8 aI = *(const shortx8*)&QI[xt * 16 + lrow][ks * 32 + kg * 8];
            shortx8 bR = *(const shortx8*)&KR[yt * 16 + lrow][ks * 32 + kg * 8];
            shortx8 bI = *(const shortx8*)&KI[yt * 16 + lrow][ks * 32 + kg * 8];
            p1 = __builtin_amdgcn_mfma_f32_16x16x32_bf16(aR, bR, p1, 0, 0, 0);
            p2 = __builtin_amdgcn_mfma_f32_16x16x32_bf16(aI, bI, p2, 0, 0, 0);
            p3 = __builtin_amdgcn_mfma_f32_16x16x32_bf16(aR, bI, p3, 0, 0, 0);
            p4 = __builtin_amdgcn_mfma_f32_16x16x32_bf16(aI, bR, p4, 0, 0, 0);
        }
#pragma unroll
        for (int r = 0; r < 4; ++r) {
            int x = xt * 16 + kg * 4 + r, y = yt * 16 + lrow;
            float re = p1[r] - p2[r], im = p3[r] + p4[r];
            float aa = fminf(fmaxf(2.f * re, -30.f), 30.f);
            float b2 = 2.f * im;
            float den = coshf(aa) + cosf(b2);
            TR[x][y] = f2bf_n(sinhf(aa) / den);
            TI[x][y] = f2bf_n(sinf(b2) / den);
        }
    }
    __syncthreads();
    // step 2: out[x][e] = sum_y t[x][y]*k[y][e]; M=32 x N=64 x K=32
    {
        int xt = wid >> 1;
        shortx8 aR = *(const shortx8*)&TR[xt * 16 + lrow][kg * 8];
        shortx8 aI = *(const shortx8*)&TI[xt * 16 + lrow][kg * 8];
#pragma unroll
        for (int ei = 0; ei < 2; ++ei) {
            int et = (wid & 1) * 2 + ei;
            shortx8 bR = *(const shortx8*)&KTR[et * 16 + lrow][kg * 8];
            shortx8 bI = *(const shortx8*)&KTI[et * 16 + lrow][kg * 8];
            f32x4 p1 = {}, p2 = {}, p3 = {}, p4 = {};
            p1 = __builtin_amdgcn_mfma_f32_16x16x32_bf16(aR, bR, p1, 0, 0, 0);
            p2 = __builtin_amdgcn_mfma_f32_16x16x32_bf16(aI, bI, p2, 0, 0, 0);
            p3 = __builtin_amdgcn_mfma_f32_16x16x32_bf16(aR, bI, p3, 0, 0, 0);
            p4 = __builtin_amdgcn_mfma_f32_16x16x32_bf16(aI, bR, p4, 0, 0, 0);
#pragma unroll
            for (int r = 0; r < 4; ++r) {
                int x = xt * 16 + kg * 4 + r, e = et * 16 + lrow;
                kf[((size_t)(h * MODES + x) * B + b) * E + e] = make_float2(p1[r] - p2[r], p3[r] + p4[r]);
            }
        }
    }
}

// sigma + prior fused
__global__ __launch_bounds__(256) void sigma_prior(const unsigned short* __restrict__ enc,
                                                   const float* __restrict__ w,
                                                   const float* __restrict__ bias,
                                                   float* __restrict__ sig_out, float* __restrict__ prior)
{
    __shared__ float wsh[H][D];
    for (int i = threadIdx.x; i < H * D; i += 256) wsh[i / D][i % D] = w[i];
    __syncthreads();
    int wid = threadIdx.x / 64, lane = threadIdx.x % 64;
    int row = blockIdx.x * 4 + wid;
    const unsigned short* p = enc + (size_t)row * D;
    float xv[8];
#pragma unroll
    for (int i = 0; i < 8; ++i) xv[i] = bf2f(p[lane + i * 64]);
    int b = row / L, l = row % L;
#pragma unroll
    for (int h = 0; h < H; ++h) {
        float s = 0.f;
#pragma unroll
        for (int i = 0; i < 8; ++i) s += xv[i] * wsh[h][lane + i * 64];
        for (int off = 32; off; off >>= 1) s += __shfl_xor(s, off);
        float acc = s + bias[h];
        float sg = 1.f / (1.f + expf(-5.f * acc));
        float val = expf((sg + 1e-5f) * 1.0986122886681098f) - 1.f; // 3^u - 1
        if (lane == 0) sig_out[((size_t)b * H + h) * L + l] = val;
        float inv2 = 1.f / (2.f * val * val);
        float coef = INV_SQRT_2PI / val;
        float* pr = prior + (((size_t)b * H + h) * L + l) * L;
        for (int sc = lane; sc < L; sc += 64) {
            float d = (float)abs(l - sc);
            pr[sc] = expf(-d * d * inv2) * coef;
        }
    }
}

// series_decomp_multi via replicate-padded prefix sum
__global__ __launch_bounds__(256) void decomp_kernel(const unsigned short* __restrict__ in1,
                                                     const unsigned short* __restrict__ in2,
                                                     const float* __restrict__ w, const float* __restrict__ bc,
                                                     unsigned short* __restrict__ res, float* __restrict__ trend,
                                                     unsigned short* __restrict__ trend16, int tmode)
{
    int b = blockIdx.x / (D / 64);
    int d0 = (blockIdx.x % (D / 64)) * 64;
    __shared__ float P[125][65];
    __shared__ float qtot[4][64];
    int tid = threadIdx.x;
    int dd = tid & 63, q = tid >> 6;
    int p0 = q * 31;
    float run = 0.f;
#pragma unroll
    for (int i = 0; i < 31; ++i) {
        int p = p0 + i;
        int j = min(max(p - 12, 0), L - 1);
        size_t g = ((size_t)b * L + j) * D + d0 + dd;
        float v = bf2f(in1[g]);
        if (in2) v += bf2f(in2[g]);
        run += v;
        P[p + 1][dd] = run;
    }
    qtot[q][dd] = run;
    if (tid < 64) P[0][dd] = 0.f;
    __syncthreads();
    if (q > 0) {
        float off = qtot[0][dd];
        if (q > 1) off += qtot[1][dd];
        if (q > 2) off += qtot[2][dd];
#pragma unroll
        for (int i = 0; i < 31; ++i)
            P[p0 + i + 1][dd] += off;
    }
    __syncthreads();
    float w0 = w[0], w1 = w[1], b0 = bc[0], b1 = bc[1];
    for (int i = tid; i < L * 64; i += 256) {
        int l = i >> 6, d2 = i & 63;
        float s12 = P[l + 19][d2] - P[l + 7][d2];
        float s24 = P[l + 25][d2] - P[l + 1][d2];
        float x = P[l + 13][d2] - P[l + 12][d2];
        float m0 = s12 * (1.f / 12.f), m1 = s24 * (1.f / 24.f);
        float z0 = x * w0 + b0, z1 = x * w1 + b1;
        float zm = fmaxf(z0, z1);
        float e0 = expf(z0 - zm), e1 = expf(z1 - zm);
        float p0f = e0 / (e0 + e1);
        float mean = m0 * p0f + m1 * (1.f - p0f);
        size_t g = ((size_t)b * L + l) * D + d0 + d2;
        res[g] = f2bf_n(x - mean);
        if (tmode == 1) trend[g] = mean;
        else if (tmode == 2) {
            float tv = trend[g] + mean;
            trend[g] = tv;
            if (trend16) trend16[g] = f2bf_n(tv);
        }
    }
}

// fused my_layernorm: per-row LN then per-column mean subtract; one block per batch b.
__global__ __launch_bounds__(256) void ln_colsub(const unsigned short* __restrict__ x,
                                                 const float* __restrict__ g, const float* __restrict__ bb,
                                                 unsigned short* __restrict__ out)
{
    int b = blockIdx.x;
    __shared__ unsigned short xs[L][D];      // 100*512*2 = 102,400 B
    __shared__ float colmean[D];
    __shared__ float gs[D], bs2[D];
    int tid = threadIdx.x;
    for (int i = tid; i < L * D / 8; i += 256) {
        int l = i / 64, c8 = (i % 64) * 8;
        *(shortx8*)&xs[l][c8] = *(const shortx8*)&x[((size_t)b * L + l) * D + c8];
    }
    for (int i = tid; i < D; i += 256) { gs[i] = g[i]; bs2[i] = bb[i]; }
    __syncthreads();
    int wid = tid >> 6, lane = tid & 63;
    for (int l = wid; l < L; l += 4) {
        float v[8];
        float s = 0.f, s2 = 0.f;
#pragma unroll
        for (int i = 0; i < 8; ++i) {
            v[i] = bf2f(xs[l][lane + i * 64]);
            s += v[i]; s2 += v[i] * v[i];
        }
        for (int off = 32; off; off >>= 1) { s += __shfl_xor(s, off); s2 += __shfl_xor(s2, off); }
        float mu = s / (float)D;
        float var = s2 / (float)D - mu * mu;
        float rstd = rsqrtf(var + 1e-5f);
#pragma unroll
        for (int i = 0; i < 8; ++i) {
            int d = lane + i * 64;
            xs[l][d] = f2bf_n((v[i] - mu) * rstd * gs[d] + bs2[d]);
        }
    }
    __syncthreads();
    for (int c = tid; c < D; c += 256) {
        float s = 0.f;
        for (int l = 0; l < L; ++l) s += bf2f(xs[l][c]);
        colmean[c] = s * (1.f / (float)L);
    }
    __syncthreads();
    for (int i = tid; i < L * D; i += 256) {
        int l = i / D, c = i % D;
        out[((size_t)b * L + l) * D + c] = f2bf_n(bf2f(xs[l][c]) - colmean[c]);
    }
}

extern "C" void kernel_launch(void* const* d_in, const int* in_sizes, int n_in,
                              void* d_out, int out_size, void* d_ws, size_t ws_size,
                              hipStream_t stream)
{
    const float* x           = (const float*)d_in[0];
    const float* emb_enc_w   = (const float*)d_in[1];
    const float* emb_dec_w   = (const float*)d_in[2];
    const float* enc_proj_w  = (const float*)d_in[3];
    const float* enc_proj_b  = (const float*)d_in[4];
    const float* enc_sig_w   = (const float*)d_in[5];
    const float* enc_sig_b   = (const float*)d_in[6];
    const float* enc_four_wr = (const float*)d_in[7];
    const float* enc_four_wi = (const float*)d_in[8];
    const float* enc_ffn_w1  = (const float*)d_in[9];
    const float* enc_ffn_w2  = (const float*)d_in[10];
    const float* enc_dcmp_w  = (const float*)d_in[11];
    const float* enc_dcmp_b  = (const float*)d_in[12];
    const float* enc_norm_g  = (const float*)d_in[13];
    const float* enc_norm_b  = (const float*)d_in[14];
    const float* dec_proj_w  = (const float*)d_in[15];
    const float* dec_proj_b  = (const float*)d_in[16];
    const float* dec_four_wr = (const float*)d_in[17];
    const float* dec_four_wi = (const float*)d_in[18];
    const float* crs_proj_w  = (const float*)d_in[19];
    const float* crs_proj_b  = (const float*)d_in[20];
    const float* crs_four_wr = (const float*)d_in[21];
    const float* crs_four_wi = (const float*)d_in[22];
    const float* dec_ffn_w1  = (const float*)d_in[23];
    const float* dec_ffn_w2  = (const float*)d_in[24];
    const float* dec_dcmp_w  = (const float*)d_in[25];
    const float* dec_dcmp_b  = (const float*)d_in[26];
    const float* dec_trend_w = (const float*)d_in[27];
    const float* dec_norm_g  = (const float*)d_in[28];
    const float* dec_norm_b  = (const float*)d_in[29];
    const float* out_proj_w  = (const float*)d_in[30];
    const float* out_proj_b  = (const float*)d_in[31];

    float* ws = (float*)d_ws;
    size_t off = 0;
    float* pe    = ws + off; off += (size_t)L * D;
    float* xmean = ws + off; off += (size_t)B * CIN;
    float* bufF  = ws + off; off += BLD;           // fp32 scratch (trend Y)
    float* tacc  = ws + off; off += BLD;           // fp32 trend accumulator
    float2* xfc  = (float2*)(ws + off); off += 2 * BHEM;
    float2* kfc  = (float2*)(ws + off); off += 2 * BHEM;
    unsigned short* wtbf = (unsigned short*)(ws + off); off += (size_t)H * MODES * 2 * E * E / 2;
    // bf16 activation buffers
    unsigned short* qk16 = (unsigned short*)(ws + off); off += BLD;        // 2*BLD shorts (q|k fused, stride 1024)
    unsigned short* e16  = (unsigned short*)(ws + off); off += BLD / 2;
    unsigned short* c16  = (unsigned short*)(ws + off); off += BLD / 2;
    unsigned short* d16  = (unsigned short*)(ws + off); off += BLD / 2;
    unsigned short* h16  = (unsigned short*)(ws + off); off += BLD / 2;
    unsigned short* t16  = (unsigned short*)(ws + off); off += BLD / 2;
    unsigned short* im16 = (unsigned short*)(ws + off); off += (size_t)M_ROWS * KEMB / 2;
    // bf16 weights + twiddle tables
    unsigned short* wbf_encproj = (unsigned short*)(ws + off); off += (size_t)2 * 4 * D * D / 2;
    unsigned short* wbf_ffn1    = (unsigned short*)(ws + off); off += (size_t)2 * DFF * D / 2;
    unsigned short* wbf_ffn2    = (unsigned short*)(ws + off); off += (size_t)2 * D * DFF / 2;
    unsigned short* wbf_decproj = (unsigned short*)(ws + off); off += (size_t)4 * D * D / 2;
    unsigned short* wbf_crsproj = (unsigned short*)(ws + off); off += (size_t)4 * D * D / 2;
    unsigned short* wbf_dffn1   = (unsigned short*)(ws + off); off += (size_t)DFF * D / 2;
    unsigned short* wbf_dffn2   = (unsigned short*)(ws + off); off += (size_t)D * DFF / 2;
    unsigned short* wbf_embenc  = (unsigned short*)(ws + off); off += (size_t)D * KEMB / 2;
    unsigned short* wbf_embdec  = (unsigned short*)(ws + off); off += (size_t)D * KEMB / 2;
    unsigned short* wbf_trd     = (unsigned short*)(ws + off); off += (size_t)192 * D / 2;
    unsigned short* wbf_seas    = (unsigned short*)(ws + off); off += (size_t)64 * D / 2;
    unsigned short* twf         = (unsigned short*)(ws + off); off += (size_t)64 * 128 / 2;
    unsigned short* twi         = (unsigned short*)(ws + off); off += (size_t)128 * 64 / 2;
    unsigned short* a16 = qk16;               // decoder reuse of qk region
    unsigned short* b16 = qk16 + BLD;

    float* out       = (float*)d_out;
    float* dec_out   = out;
    float* series_out= out + (size_t)B * L * COUT;
    float* prior_out = series_out + 2 * BHLL;
    float* sigma_out = prior_out + 2 * BHLL;

    const int BH = B * H;

    init_consts<<<200, 256, 0, stream>>>(pe);
    init_tw<<<32, 256, 0, stream>>>(twf, twi);
    xmean_kernel<<<cdiv(B * CIN, 256), 256, 0, stream>>>(x, xmean);

    // merged weight prep (7 bulk bf16 conversions + 4 padded layouts) in ONE launch
    PrepArgs pa;
    pa.src[0] = enc_proj_w; pa.dst[0] = wbf_encproj; pa.n4[0] = 2 * 4 * D * D / 4;
    pa.src[1] = enc_ffn_w1; pa.dst[1] = wbf_ffn1;    pa.n4[1] = 2 * DFF * D / 4;
    pa.src[2] = enc_ffn_w2; pa.dst[2] = wbf_ffn2;    pa.n4[2] = 2 * D * DFF / 4;
    pa.src[3] = dec_proj_w; pa.dst[3] = wbf_decproj; pa.n4[3] = 4 * D * D / 4;
    pa.src[4] = crs_proj_w; pa.dst[4] = wbf_crsproj; pa.n4[4] = 4 * D * D / 4;
    pa.src[5] = dec_ffn_w1; pa.dst[5] = wbf_dffn1;   pa.n4[5] = DFF * D / 4;
    pa.src[6] = dec_ffn_w2; pa.dst[6] = wbf_dffn2;   pa.n4[6] = D * DFF / 4;
    pa.emb_enc = emb_enc_w; pa.emb_dec = emb_dec_w; pa.trend_w = dec_trend_w; pa.seas_w = out_proj_w;
    pa.d_embenc = wbf_embenc; pa.d_embdec = wbf_embdec; pa.d_trd = wbf_trd; pa.d_seas = wbf_seas;
    int total4 = 0;
    for (int s = 0; s < 7; ++s) total4 += pa.n4[s];
    int padTotal = 2 * D * KEMB + 192 * D + 64 * D;
    prep_all<<<2048, 256, 0, stream>>>(pa, total4, padTotal);
    transpose_wb<<<H * E, 256, 0, stream>>>(enc_four_wr, enc_four_wi, wtbf);

    auto gemm = [&](const unsigned short* A, const unsigned short* Wb, const float* bias, const float* pe_,
                    float* C, unsigned short* Cb, int N, int Nout, int K, int act, int accum) {
        if (N % 128 == 0) {
            dim3 grid(N / 128, M_ROWS / 128);
            gemm_mfma<128><<<grid, 256, 0, stream>>>(A, Wb, bias, pe_, C, Cb, Nout, K, act, accum);
        } else {
            dim3 grid(N / 64, M_ROWS / 128);
            gemm_mfma<64><<<grid, 256, 0, stream>>>(A, Wb, bias, pe_, C, Cb, Nout, K, act, accum);
        }
    };
    dim3 mg_grid(H * MODES, B / 32);
    dim3 sc_grid(BH, 2);

    // encoder embedding
    im2col_emb<<<cdiv(M_ROWS * KEMB, 256), 256, 0, stream>>>(x, nullptr, im16);
    gemm(im16, wbf_embenc, nullptr, pe, nullptr, e16, D, D, KEMB, 0, 0);

    for (int i = 0; i < 2; ++i) {
        const unsigned short* Wp = wbf_encproj + (size_t)i * 4 * D * D;
        const float* bp = enc_proj_b + (size_t)i * 4 * D;
        float* series_i = series_out + (size_t)i * BHLL;
        float* prior_i  = prior_out  + (size_t)i * BHLL;
        float* sigma_i  = sigma_out  + (size_t)i * B * H * L;

        gemm(e16, Wp, bp, nullptr, nullptr, qk16, 1024, 1024, D, 0, 0);       // fused q+k
        dft_mfma<<<BH, 256, 0, stream>>>(qk16, twf, xfc, 1024);
        mode_gemm_mfma<<<mg_grid, 256, 0, stream>>>(xfc, wtbf);
        idft_mfma<<<BH, 256, 0, stream>>>(xfc, twi, c16, 1.f / (float)L);
        gemm(c16, Wp + (size_t)3 * D * D, bp + 3 * D, nullptr, nullptr, d16, D, D, D, 0, 0); // attn_out
        scores_softmax<<<sc_grid, 256, 0, stream>>>(qk16, series_i);
        sigma_prior<<<M_ROWS / 4, 256, 0, stream>>>(e16, enc_sig_w + (size_t)i * H * D,
                                                    enc_sig_b + (size_t)i * H, sigma_i, prior_i);
        decomp_kernel<<<B * (D / 64), 256, 0, stream>>>(e16, d16, enc_dcmp_w + (size_t)(i * 2 + 0) * NK,
                                                        enc_dcmp_b + (size_t)(i * 2 + 0) * NK, h16, nullptr, nullptr, 0);
        gemm(h16, wbf_ffn1 + (size_t)i * DFF * D, nullptr, nullptr, nullptr, c16, DFF, DFF, D, 1, 0);
        gemm(c16, wbf_ffn2 + (size_t)i * D * DFF, nullptr, nullptr, nullptr, d16, D, D, DFF, 0, 0);
        decomp_kernel<<<B * (D / 64), 256, 0, stream>>>(h16, d16, enc_dcmp_w + (size_t)(i * 2 + 1) * NK,
                                                        enc_dcmp_b + (size_t)(i * 2 + 1) * NK, e16, nullptr, nullptr, 0);
    }
    // encoder final my_layernorm (fused LN + column-mean subtract), in place on e16
    ln_colsub<<<B, 256, 0, stream>>>(e16, enc_norm_g, enc_norm_b, e16);

    // ---------------- decoder ----------------
    transpose_wb<<<H * E, 256, 0, stream>>>(dec_four_wr, dec_four_wi, wtbf);
    im2col_emb<<<cdiv(M_ROWS * KEMB, 256), 256, 0, stream>>>(x, xmean, im16);
    gemm(im16, wbf_embdec, nullptr, pe, nullptr, a16, D, D, KEMB, 0, 0);           // dec
    gemm(a16, wbf_decproj, dec_proj_b, nullptr, nullptr, b16, D, D, D, 0, 0);      // q
    dft_mfma<<<BH, 256, 0, stream>>>(b16, twf, xfc, D);
    mode_gemm_mfma<<<mg_grid, 256, 0, stream>>>(xfc, wtbf);
    idft_mfma<<<BH, 256, 0, stream>>>(xfc, twi, c16, 1.f / (float)L);
    gemm(c16, wbf_decproj + (size_t)3 * D * D, dec_proj_b + 3 * D, nullptr, nullptr, d16, D, D, D, 0, 0); // sa
    decomp_kernel<<<B * (D / 64), 256, 0, stream>>>(a16, d16, dec_dcmp_w, dec_dcmp_b, h16, tacc, nullptr, 1); // h, t1

    gemm(h16, wbf_crsproj, crs_proj_b, nullptr, nullptr, b16, D, D, D, 0, 0);      // qc
    dft_mfma<<<BH, 256, 0, stream>>>(b16, twf, xfc, D);                            // qf
    gemm(e16, wbf_crsproj + (size_t)D * D, crs_proj_b + D, nullptr, nullptr, b16, D, D, D, 0, 0); // kc
    dft_mfma<<<BH, 256, 0, stream>>>(b16, twf, kfc, D);                            // kf
    transpose_wb<<<H * E, 256, 0, stream>>>(crs_four_wr, crs_four_wi, wtbf);
    fourier_qk_mfma<<<BH, 256, 0, stream>>>(xfc, kfc);                             // kfc := qkv
    mode_gemm_mfma<<<mg_grid, 256, 0, stream>>>(kfc, wtbf);
    idft_mfma<<<BH, 256, 0, stream>>>(kfc, twi, c16, 1.f / ((float)L * (float)D * (float)D));
    gemm(c16, wbf_crsproj + (size_t)3 * D * D, crs_proj_b + 3 * D, nullptr, nullptr, d16, D, D, D, 0, 0); // ca
    decomp_kernel<<<B * (D / 64), 256, 0, stream>>>(h16, d16, dec_dcmp_w + NK, dec_dcmp_b + NK, a16, tacc, nullptr, 2); // h2, t2

    gemm(a16, wbf_dffn1, nullptr, nullptr, nullptr, c16, DFF, DFF, D, 1, 0);
    gemm(c16, wbf_dffn2, nullptr, nullptr, nullptr, d16, D, D, DFF, 0, 0);
    decomp_kernel<<<B * (D / 64), 256, 0, stream>>>(a16, d16, dec_dcmp_w + 2 * NK, dec_dcmp_b + 2 * NK, b16, tacc, t16, 2); // h3, t3 (+bf16 trend)

    // trend conv: stacked-tap GEMM (K=512, N=192, fp32 out) -> combine with trend_init (xmean)
    gemm(t16, wbf_trd, nullptr, nullptr, bufF, nullptr, 192, 192, D, 0, 0);
    trend_combine<<<cdiv(B * L * COUT, 256), 256, 0, stream>>>(bufF, xmean, dec_out);

    // final layernorm (fused) + seasonal projection accumulated into dec_out
    ln_colsub<<<B, 256, 0, stream>>>(b16, dec_norm_g, dec_norm_b, d16);
    gemm(d16, wbf_seas, out_proj_b, nullptr, dec_out, nullptr, 64, COUT, D, 0, 1);
}